// Round 5
// baseline (4350.228 us; speedup 1.0000x reference)
//
#include <hip/hip_runtime.h>

#define N_NODES 50000
#define N_EDGES 500000
#define IN_DIM  256
#define HID     128
#define OUT_DIM 7
#define NPAIRS  100000
#define BATCH   65536
#define BN_EPS  1e-5f

#define BM 64
#define BK 16

// ---------------- edge aggregation: agg[dst] += h[src] ----------------
// one thread per (edge, float4 chunk)
__global__ void agg_kernel(const float* __restrict__ h,
                           const int* __restrict__ src,
                           const int* __restrict__ dst,
                           float* __restrict__ agg,
                           int nEdges, int D, int cshift) {
  int t = blockIdx.x * blockDim.x + threadIdx.x;
  int chunks = D >> 2;
  int total = nEdges << cshift;
  if (t >= total) return;
  int e = t >> cshift;
  int c = t & (chunks - 1);
  int s = src[e];
  int d = dst[e];
  float4 v = ((const float4*)(h + (size_t)s * D))[c];
  float* p = agg + (size_t)d * D + (size_t)c * 4;
  atomicAdd(p + 0, v.x);
  atomicAdd(p + 1, v.y);
  atomicAdd(p + 2, v.z);
  atomicAdd(p + 3, v.w);
}

// ---------------- generic tiled GEMM, N fixed = 128 ----------------
// C[M,128] = epilogue( (scale*A1 + A2) @ W + bias ), scale = 1+eps[layer] if A2
// epilogue: relu, then optional BN (inference) + relu
__global__ __launch_bounds__(256) void mm_kernel(
    const float* __restrict__ A1,
    const float* __restrict__ A2,    // may be null
    const float* __restrict__ epsP,  // may be null
    int layer,
    const float* __restrict__ W,     // K x 128 row-major
    const float* __restrict__ bias,  // 128
    const float* __restrict__ gamma, const float* __restrict__ beta,
    const float* __restrict__ mean,  const float* __restrict__ var,
    float* __restrict__ C,
    int M, int K, int do_bn)
{
  __shared__ float As[BM][BK + 1];   // +1 pad: conflict-free As[r][k] reads
  __shared__ float Ws[BK][HID];

  int tid = threadIdx.x;
  int row0 = blockIdx.x * BM;
  int r  = tid >> 2;     // 0..63
  int cg = tid & 3;      // 0..3  (cols cg + 4*j)
  int row = row0 + r;

  float scale = 1.0f;
  if (A2) scale = 1.0f + epsP[layer];

  float acc[32];
#pragma unroll
  for (int j = 0; j < 32; ++j) acc[j] = 0.0f;

  for (int kk = 0; kk < K; kk += BK) {
    // A tile: thread loads A[row][kk + cg*4 .. +3]
    float4 a = make_float4(0.f, 0.f, 0.f, 0.f);
    if (row < M) {
      a = *(const float4*)(A1 + (size_t)row * K + kk + cg * 4);
      if (A2) {
        float4 a2 = *(const float4*)(A2 + (size_t)row * K + kk + cg * 4);
        a.x = scale * a.x + a2.x;
        a.y = scale * a.y + a2.y;
        a.z = scale * a.z + a2.z;
        a.w = scale * a.w + a2.w;
      }
    }
    int kc = cg * 4;
    As[r][kc + 0] = a.x; As[r][kc + 1] = a.y;
    As[r][kc + 2] = a.z; As[r][kc + 3] = a.w;

    // W tile: 16x128 floats = 512 float4, 256 threads -> 2 each
#pragma unroll
    for (int i = 0; i < 2; ++i) {
      int l = tid + i * 256;
      int wr = l >> 5;
      int wc = (l & 31) * 4;
      float4 w = *(const float4*)(W + (size_t)(kk + wr) * HID + wc);
      *(float4*)&Ws[wr][wc] = w;
    }
    __syncthreads();

#pragma unroll
    for (int k = 0; k < BK; ++k) {
      float av = As[r][k];
#pragma unroll
      for (int j = 0; j < 32; ++j) {
        acc[j] = fmaf(av, Ws[k][cg + 4 * j], acc[j]);
      }
    }
    __syncthreads();
  }

  if (row < M) {
    float* cp = C + (size_t)row * HID;
#pragma unroll
    for (int j = 0; j < 32; ++j) {
      int c = cg + 4 * j;
      float v = acc[j] + bias[c];
      v = fmaxf(v, 0.0f);
      if (do_bn) {
        float s = gamma[c] * rsqrtf(var[c] + BN_EPS);
        float t = beta[c] - mean[c] * s;
        v = fmaf(v, s, t);
        v = fmaxf(v, 0.0f);
      }
      cp[c] = v;
    }
  }
}

// ---------------- pair-gather GEMM: Z = [h[p0], h[p1]] (65536 x 256) ----------------
__global__ __launch_bounds__(256) void mm_pairs_kernel(
    const float* __restrict__ h,    // N_NODES x 128
    const int* __restrict__ ppi,    // NPAIRS x 2
    const int* __restrict__ idx,    // BATCH
    const float* __restrict__ W,    // 256 x 128
    const float* __restrict__ bias, // 128
    float* __restrict__ C)          // BATCH x 128
{
  __shared__ float As[BM][BK + 1];
  __shared__ float Ws[BK][HID];

  int tid = threadIdx.x;
  int row0 = blockIdx.x * BM;
  int r  = tid >> 2;
  int cg = tid & 3;
  int row = row0 + r;     // BATCH divisible by 64, no guards

  int pi = idx[row];
  int n0 = ppi[2 * pi];
  int n1 = ppi[2 * pi + 1];

  float acc[32];
#pragma unroll
  for (int j = 0; j < 32; ++j) acc[j] = 0.0f;

  for (int kk = 0; kk < 2 * HID; kk += BK) {
    int node = (kk >= HID) ? n1 : n0;
    int kc = (kk & (HID - 1)) + cg * 4;
    float4 a = *(const float4*)(h + (size_t)node * HID + kc);
    int kl = cg * 4;
    As[r][kl + 0] = a.x; As[r][kl + 1] = a.y;
    As[r][kl + 2] = a.z; As[r][kl + 3] = a.w;

#pragma unroll
    for (int i = 0; i < 2; ++i) {
      int l = tid + i * 256;
      int wr = l >> 5;
      int wc = (l & 31) * 4;
      float4 w = *(const float4*)(W + (size_t)(kk + wr) * HID + wc);
      *(float4*)&Ws[wr][wc] = w;
    }
    __syncthreads();

#pragma unroll
    for (int k = 0; k < BK; ++k) {
      float av = As[r][k];
#pragma unroll
      for (int j = 0; j < 32; ++j) {
        acc[j] = fmaf(av, Ws[k][cg + 4 * j], acc[j]);
      }
    }
    __syncthreads();
  }

  float* cp = C + (size_t)row * HID;
#pragma unroll
  for (int j = 0; j < 32; ++j) {
    int c = cg + 4 * j;
    float v = acc[j] + bias[c];
    cp[c] = fmaxf(v, 0.0f);
  }
}

// ---------------- final 128 -> 7 head, one wave per row ----------------
__global__ void final_kernel(const float* __restrict__ z,   // BATCH x 128
                             const float* __restrict__ w2,  // 128 x 7
                             const float* __restrict__ b2,  // 7
                             float* __restrict__ out) {     // BATCH x 7
  int row = blockIdx.x;
  int lane = threadIdx.x;  // 0..63
  float a0 = z[(size_t)row * HID + lane];
  float a1 = z[(size_t)row * HID + 64 + lane];
#pragma unroll
  for (int o = 0; o < OUT_DIM; ++o) {
    float p = a0 * w2[lane * OUT_DIM + o] + a1 * w2[(64 + lane) * OUT_DIM + o];
#pragma unroll
    for (int s = 32; s > 0; s >>= 1) p += __shfl_down(p, s);
    if (lane == 0) out[(size_t)row * OUT_DIM + o] = p + b2[o];
  }
}

extern "C" void kernel_launch(void* const* d_in, const int* in_sizes, int n_in,
                              void* d_out, int out_size, void* d_ws, size_t ws_size,
                              hipStream_t stream) {
  const float* feat   = (const float*)d_in[0];
  const int*   src    = (const int*)d_in[1];
  const int*   dst    = (const int*)d_in[2];
  const int*   ppi    = (const int*)d_in[3];
  const int*   idx    = (const int*)d_in[4];
  const float* eps    = (const float*)d_in[5];
  const float* w1_in  = (const float*)d_in[6];
  const float* b1_in  = (const float*)d_in[7];
  const float* w2_in  = (const float*)d_in[8];
  const float* b2_in  = (const float*)d_in[9];
  const float* hw1    = (const float*)d_in[10];
  const float* hb1    = (const float*)d_in[11];
  const float* hw2    = (const float*)d_in[12];
  const float* hb2    = (const float*)d_in[13];
  const float* bng    = (const float*)d_in[14];
  const float* bnb    = (const float*)d_in[15];
  const float* bnm    = (const float*)d_in[16];
  const float* bnv    = (const float*)d_in[17];
  const float* lin_w  = (const float*)d_in[18];
  const float* lin_b  = (const float*)d_in[19];
  const float* int_w1 = (const float*)d_in[20];
  const float* int_b1 = (const float*)d_in[21];
  const float* int_w2 = (const float*)d_in[22];
  const float* int_b2 = (const float*)d_in[23];
  float* out = (float*)d_out;

  float* ws  = (float*)d_ws;
  float* agg = ws;                                  // 50000*256 floats
  float* hA  = agg + (size_t)N_NODES * IN_DIM;      // 50000*128
  float* hB  = hA + (size_t)N_NODES * HID;          // 50000*128
  float* zb  = agg;                                 // aliased: agg dead before zb written

  int mmBlocks = (N_NODES + BM - 1) / BM;

  // ---- layer 1 (256-dim input) ----
  hipMemsetAsync(agg, 0, (size_t)N_NODES * IN_DIM * sizeof(float), stream);
  {
    int total = N_EDGES * (IN_DIM / 4);
    agg_kernel<<<(total + 255) / 256, 256, 0, stream>>>(feat, src, dst, agg,
                                                        N_EDGES, IN_DIM, 6);
  }
  mm_kernel<<<mmBlocks, 256, 0, stream>>>(feat, agg, eps, 0, w1_in, b1_in,
                                          nullptr, nullptr, nullptr, nullptr,
                                          hA, N_NODES, IN_DIM, 0);
  mm_kernel<<<mmBlocks, 256, 0, stream>>>(hA, nullptr, nullptr, 0, w2_in, b2_in,
                                          bng, bnb, bnm, bnv,
                                          hB, N_NODES, HID, 1);

  // ---- layers 2..3 (128-dim) ----
  for (int l = 1; l < 3; ++l) {
    hipMemsetAsync(agg, 0, (size_t)N_NODES * HID * sizeof(float), stream);
    int total = N_EDGES * (HID / 4);
    agg_kernel<<<(total + 255) / 256, 256, 0, stream>>>(hB, src, dst, agg,
                                                        N_EDGES, HID, 5);
    mm_kernel<<<mmBlocks, 256, 0, stream>>>(hB, agg, eps, l,
                                            hw1 + (size_t)(l - 1) * HID * HID,
                                            hb1 + (size_t)(l - 1) * HID,
                                            nullptr, nullptr, nullptr, nullptr,
                                            hA, N_NODES, HID, 0);
    mm_kernel<<<mmBlocks, 256, 0, stream>>>(hA, nullptr, nullptr, 0,
                                            hw2 + (size_t)(l - 1) * HID * HID,
                                            hb2 + (size_t)(l - 1) * HID,
                                            bng + l * HID, bnb + l * HID,
                                            bnm + l * HID, bnv + l * HID,
                                            hB, N_NODES, HID, 1);
  }

  // ---- lin ----
  mm_kernel<<<mmBlocks, 256, 0, stream>>>(hB, nullptr, nullptr, 0, lin_w, lin_b,
                                          nullptr, nullptr, nullptr, nullptr,
                                          hA, N_NODES, HID, 0);

  // ---- pair head ----
  mm_pairs_kernel<<<BATCH / BM, 256, 0, stream>>>(hA, ppi, idx, int_w1, int_b1, zb);
  final_kernel<<<BATCH, 64, 0, stream>>>(zb, int_w2, int_b2, out);
}

// Round 6
// 1273.133 us; speedup vs baseline: 3.4169x; 3.4169x over previous
//
#include <hip/hip_runtime.h>

#define N_NODES 50000
#define N_EDGES 500000
#define IN_DIM  256
#define HID     128
#define OUT_DIM 7
#define NPAIRS  100000
#define BATCH   65536
#define BN_EPS  1e-5f

#define BM 64
#define BK 16

// ================= CSR build (once per call) =================
// deg/cursor share one array: used as degree counts, then rewritten to
// exclusive-prefix cursors by the scan kernel.

__global__ void hist_kernel(const int* __restrict__ dst, int* __restrict__ deg) {
  int e = blockIdx.x * blockDim.x + threadIdx.x;
  if (e < N_EDGES) atomicAdd(&deg[dst[e]], 1);
}

// single-block exclusive scan of 50000 degrees -> row_ptr, cursor
__global__ __launch_bounds__(1024) void scan_kernel(int* __restrict__ deg_cursor,
                                                    int* __restrict__ row_ptr) {
  __shared__ int partial[1024];
  const int CH = (N_NODES + 1023) / 1024;  // 49 nodes per thread
  int tid = threadIdx.x;
  int base = tid * CH;

  int sum = 0;
  for (int i = 0; i < CH; ++i) {
    int n = base + i;
    if (n < N_NODES) sum += deg_cursor[n];
  }
  partial[tid] = sum;
  __syncthreads();
  // inclusive Hillis-Steele scan over 1024 partials
  for (int off = 1; off < 1024; off <<= 1) {
    int v = (tid >= off) ? partial[tid - off] : 0;
    __syncthreads();
    partial[tid] += v;
    __syncthreads();
  }
  int run = partial[tid] - sum;  // exclusive prefix of this chunk
  for (int i = 0; i < CH; ++i) {
    int n = base + i;
    if (n < N_NODES) {
      int dn = deg_cursor[n];   // read BEFORE overwrite (aliased)
      row_ptr[n] = run;
      deg_cursor[n] = run;      // becomes scatter cursor
      run += dn;
    }
  }
  if (tid == 1023) row_ptr[N_NODES] = run;  // == N_EDGES
}

__global__ void scatter_kernel(const int* __restrict__ src,
                               const int* __restrict__ dst,
                               int* __restrict__ cursor,
                               int* __restrict__ esrc) {
  int e = blockIdx.x * blockDim.x + threadIdx.x;
  if (e < N_EDGES) {
    int pos = atomicAdd(&cursor[dst[e]], 1);
    esrc[pos] = src[e];
  }
}

// ================= fused aggregate: x[d] = (1+eps)*h[d] + sum_{s in in(d)} h[s] =================
// one wave per node; lane covers D/64 contiguous floats -> coalesced 512B/1KB row reads
template <int D>
__global__ __launch_bounds__(256) void gather_kernel(
    const float* __restrict__ h,
    const int* __restrict__ row_ptr,
    const int* __restrict__ esrc,
    const float* __restrict__ epsP, int layer,
    float* __restrict__ x)
{
  int wave = (blockIdx.x * blockDim.x + threadIdx.x) >> 6;
  int lane = threadIdx.x & 63;
  if (wave >= N_NODES) return;
  int beg = row_ptr[wave];
  int end = row_ptr[wave + 1];
  float scale = 1.0f + epsP[layer];

  if (D == 128) {
    float2 acc = *(const float2*)(h + (size_t)wave * D + lane * 2);
    acc.x *= scale; acc.y *= scale;
    for (int i = beg; i < end; ++i) {
      int s = esrc[i];
      float2 v = *(const float2*)(h + (size_t)s * D + lane * 2);
      acc.x += v.x; acc.y += v.y;
    }
    *(float2*)(x + (size_t)wave * D + lane * 2) = acc;
  } else {
    float4 acc = *(const float4*)(h + (size_t)wave * D + lane * 4);
    acc.x *= scale; acc.y *= scale; acc.z *= scale; acc.w *= scale;
    for (int i = beg; i < end; ++i) {
      int s = esrc[i];
      float4 v = *(const float4*)(h + (size_t)s * D + lane * 4);
      acc.x += v.x; acc.y += v.y; acc.z += v.z; acc.w += v.w;
    }
    *(float4*)(x + (size_t)wave * D + lane * 4) = acc;
  }
}

// ================= tiled GEMM, N fixed = 128 =================
// C[M,128] = epilogue( A @ W + bias ); epilogue: relu, then optional BN + relu
__global__ __launch_bounds__(256) void mm_kernel(
    const float* __restrict__ A,
    const float* __restrict__ W,     // K x 128 row-major
    const float* __restrict__ bias,  // 128
    const float* __restrict__ gamma, const float* __restrict__ beta,
    const float* __restrict__ mean,  const float* __restrict__ var,
    float* __restrict__ C,
    int M, int K, int do_bn)
{
  __shared__ float As[BM][BK + 1];
  __shared__ float Ws[BK][HID];

  int tid = threadIdx.x;
  int row0 = blockIdx.x * BM;
  int r  = tid >> 2;     // 0..63
  int cg = tid & 3;      // 0..3
  int row = row0 + r;

  float acc[32];
#pragma unroll
  for (int j = 0; j < 32; ++j) acc[j] = 0.0f;

  for (int kk = 0; kk < K; kk += BK) {
    float4 a = make_float4(0.f, 0.f, 0.f, 0.f);
    if (row < M) a = *(const float4*)(A + (size_t)row * K + kk + cg * 4);
    int kc = cg * 4;
    As[r][kc + 0] = a.x; As[r][kc + 1] = a.y;
    As[r][kc + 2] = a.z; As[r][kc + 3] = a.w;

#pragma unroll
    for (int i = 0; i < 2; ++i) {
      int l = tid + i * 256;
      int wr = l >> 5;
      int wc = (l & 31) * 4;
      float4 w = *(const float4*)(W + (size_t)(kk + wr) * HID + wc);
      *(float4*)&Ws[wr][wc] = w;
    }
    __syncthreads();

#pragma unroll
    for (int k = 0; k < BK; ++k) {
      float av = As[r][k];
#pragma unroll
      for (int j = 0; j < 32; ++j) {
        acc[j] = fmaf(av, Ws[k][cg + 4 * j], acc[j]);
      }
    }
    __syncthreads();
  }

  if (row < M) {
    float* cp = C + (size_t)row * HID;
#pragma unroll
    for (int j = 0; j < 32; ++j) {
      int c = cg + 4 * j;
      float v = acc[j] + bias[c];
      v = fmaxf(v, 0.0f);
      if (do_bn) {
        float s = gamma[c] * rsqrtf(var[c] + BN_EPS);
        float t = beta[c] - mean[c] * s;
        v = fmaf(v, s, t);
        v = fmaxf(v, 0.0f);
      }
      cp[c] = v;
    }
  }
}

// ================= pair-gather GEMM: Z = relu([h[p0], h[p1]] @ W + b) =================
__global__ __launch_bounds__(256) void mm_pairs_kernel(
    const float* __restrict__ h,    // N_NODES x 128
    const int* __restrict__ ppi,    // NPAIRS x 2
    const int* __restrict__ idx,    // BATCH
    const float* __restrict__ W,    // 256 x 128
    const float* __restrict__ bias, // 128
    float* __restrict__ C)          // BATCH x 128
{
  __shared__ float As[BM][BK + 1];
  __shared__ float Ws[BK][HID];

  int tid = threadIdx.x;
  int row0 = blockIdx.x * BM;
  int r  = tid >> 2;
  int cg = tid & 3;
  int row = row0 + r;     // BATCH divisible by 64

  int pi = idx[row];
  int n0 = ppi[2 * pi];
  int n1 = ppi[2 * pi + 1];

  float acc[32];
#pragma unroll
  for (int j = 0; j < 32; ++j) acc[j] = 0.0f;

  for (int kk = 0; kk < 2 * HID; kk += BK) {
    int node = (kk >= HID) ? n1 : n0;
    int kc = (kk & (HID - 1)) + cg * 4;
    float4 a = *(const float4*)(h + (size_t)node * HID + kc);
    int kl = cg * 4;
    As[r][kl + 0] = a.x; As[r][kl + 1] = a.y;
    As[r][kl + 2] = a.z; As[r][kl + 3] = a.w;

#pragma unroll
    for (int i = 0; i < 2; ++i) {
      int l = tid + i * 256;
      int wr = l >> 5;
      int wc = (l & 31) * 4;
      float4 w = *(const float4*)(W + (size_t)(kk + wr) * HID + wc);
      *(float4*)&Ws[wr][wc] = w;
    }
    __syncthreads();

#pragma unroll
    for (int k = 0; k < BK; ++k) {
      float av = As[r][k];
#pragma unroll
      for (int j = 0; j < 32; ++j) {
        acc[j] = fmaf(av, Ws[k][cg + 4 * j], acc[j]);
      }
    }
    __syncthreads();
  }

  float* cp = C + (size_t)row * HID;
#pragma unroll
  for (int j = 0; j < 32; ++j) {
    int c = cg + 4 * j;
    float v = acc[j] + bias[c];
    cp[c] = fmaxf(v, 0.0f);
  }
}

// ================= final 128 -> 7 head =================
__global__ void final_kernel(const float* __restrict__ z,
                             const float* __restrict__ w2,
                             const float* __restrict__ b2,
                             float* __restrict__ out) {
  int row = blockIdx.x;
  int lane = threadIdx.x;  // 0..63
  float a0 = z[(size_t)row * HID + lane];
  float a1 = z[(size_t)row * HID + 64 + lane];
#pragma unroll
  for (int o = 0; o < OUT_DIM; ++o) {
    float p = a0 * w2[lane * OUT_DIM + o] + a1 * w2[(64 + lane) * OUT_DIM + o];
#pragma unroll
    for (int s = 32; s > 0; s >>= 1) p += __shfl_down(p, s);
    if (lane == 0) out[(size_t)row * OUT_DIM + o] = p + b2[o];
  }
}

extern "C" void kernel_launch(void* const* d_in, const int* in_sizes, int n_in,
                              void* d_out, int out_size, void* d_ws, size_t ws_size,
                              hipStream_t stream) {
  const float* feat   = (const float*)d_in[0];
  const int*   src    = (const int*)d_in[1];
  const int*   dst    = (const int*)d_in[2];
  const int*   ppi    = (const int*)d_in[3];
  const int*   idx    = (const int*)d_in[4];
  const float* eps    = (const float*)d_in[5];
  const float* w1_in  = (const float*)d_in[6];
  const float* b1_in  = (const float*)d_in[7];
  const float* w2_in  = (const float*)d_in[8];
  const float* b2_in  = (const float*)d_in[9];
  const float* hw1    = (const float*)d_in[10];
  const float* hb1    = (const float*)d_in[11];
  const float* hw2    = (const float*)d_in[12];
  const float* hb2    = (const float*)d_in[13];
  const float* bng    = (const float*)d_in[14];
  const float* bnb    = (const float*)d_in[15];
  const float* bnm    = (const float*)d_in[16];
  const float* bnv    = (const float*)d_in[17];
  const float* lin_w  = (const float*)d_in[18];
  const float* lin_b  = (const float*)d_in[19];
  const float* int_w1 = (const float*)d_in[20];
  const float* int_b1 = (const float*)d_in[21];
  const float* int_w2 = (const float*)d_in[22];
  const float* int_b2 = (const float*)d_in[23];
  float* out = (float*)d_out;

  float* ws   = (float*)d_ws;
  float* xbuf = ws;                                   // 50000*256 f32 (fused (1+eps)h+agg)
  float* hA   = xbuf + (size_t)N_NODES * IN_DIM;      // 50000*128
  float* hB   = hA + (size_t)N_NODES * HID;           // 50000*128
  int*   row_ptr = (int*)(hB + (size_t)N_NODES * HID);// 50001 (+pad)
  int*   cursor  = row_ptr + N_NODES + 8;             // 50000 (deg, then cursor)
  int*   esrc    = cursor + N_NODES;                  // 500000
  float* zb   = xbuf;                                 // alias: xbuf dead after lin GEMM

  int mmBlocks = (N_NODES + BM - 1) / BM;
  int edgeBlocks = (N_EDGES + 255) / 256;
  int gatherBlocks = (N_NODES + 3) / 4;               // 4 waves/block, 1 wave/node

  // ---- CSR build (graph is identical across the 3 layers) ----
  hipMemsetAsync(cursor, 0, N_NODES * sizeof(int), stream);
  hist_kernel<<<edgeBlocks, 256, 0, stream>>>(dst, cursor);
  scan_kernel<<<1, 1024, 0, stream>>>(cursor, row_ptr);
  scatter_kernel<<<edgeBlocks, 256, 0, stream>>>(src, dst, cursor, esrc);

  // ---- layer 1 (256-dim input) ----
  gather_kernel<IN_DIM><<<gatherBlocks, 256, 0, stream>>>(feat, row_ptr, esrc, eps, 0, xbuf);
  mm_kernel<<<mmBlocks, 256, 0, stream>>>(xbuf, w1_in, b1_in,
                                          nullptr, nullptr, nullptr, nullptr,
                                          hA, N_NODES, IN_DIM, 0);
  mm_kernel<<<mmBlocks, 256, 0, stream>>>(hA, w2_in, b2_in,
                                          bng, bnb, bnm, bnv,
                                          hB, N_NODES, HID, 1);

  // ---- layers 2..3 (128-dim) ----
  for (int l = 1; l < 3; ++l) {
    gather_kernel<HID><<<gatherBlocks, 256, 0, stream>>>(hB, row_ptr, esrc, eps, l, xbuf);
    mm_kernel<<<mmBlocks, 256, 0, stream>>>(xbuf,
                                            hw1 + (size_t)(l - 1) * HID * HID,
                                            hb1 + (size_t)(l - 1) * HID,
                                            nullptr, nullptr, nullptr, nullptr,
                                            hA, N_NODES, HID, 0);
    mm_kernel<<<mmBlocks, 256, 0, stream>>>(hA,
                                            hw2 + (size_t)(l - 1) * HID * HID,
                                            hb2 + (size_t)(l - 1) * HID,
                                            bng + l * HID, bnb + l * HID,
                                            bnm + l * HID, bnv + l * HID,
                                            hB, N_NODES, HID, 1);
  }

  // ---- lin ----
  mm_kernel<<<mmBlocks, 256, 0, stream>>>(hB, lin_w, lin_b,
                                          nullptr, nullptr, nullptr, nullptr,
                                          hA, N_NODES, HID, 0);

  // ---- pair head ----
  mm_pairs_kernel<<<BATCH / BM, 256, 0, stream>>>(hA, ppi, idx, int_w1, int_b1, zb);
  final_kernel<<<BATCH, 64, 0, stream>>>(zb, int_w2, int_b2, out);
}

// Round 7
// 1267.758 us; speedup vs baseline: 3.4314x; 1.0042x over previous
//
#include <hip/hip_runtime.h>

#define N_NODES 50000
#define N_EDGES 500000
#define IN_DIM  256
#define HID     128
#define OUT_DIM 7
#define NPAIRS  100000
#define BATCH   65536
#define BN_EPS  1e-5f

#define BM 64
#define BK 16

// ================= CSR build (once per call) =================
__global__ void hist_kernel(const int* __restrict__ dst, int* __restrict__ deg) {
  int e = blockIdx.x * blockDim.x + threadIdx.x;
  if (e < N_EDGES) atomicAdd(&deg[dst[e]], 1);
}

// single-block exclusive scan of 50000 degrees -> row_ptr, cursor
__global__ __launch_bounds__(1024) void scan_kernel(int* __restrict__ deg_cursor,
                                                    int* __restrict__ row_ptr) {
  __shared__ int partial[1024];
  const int CH = (N_NODES + 1023) / 1024;
  int tid = threadIdx.x;
  int base = tid * CH;

  int sum = 0;
  for (int i = 0; i < CH; ++i) {
    int n = base + i;
    if (n < N_NODES) sum += deg_cursor[n];
  }
  partial[tid] = sum;
  __syncthreads();
  for (int off = 1; off < 1024; off <<= 1) {
    int v = (tid >= off) ? partial[tid - off] : 0;
    __syncthreads();
    partial[tid] += v;
    __syncthreads();
  }
  int run = partial[tid] - sum;
  for (int i = 0; i < CH; ++i) {
    int n = base + i;
    if (n < N_NODES) {
      int dn = deg_cursor[n];
      row_ptr[n] = run;
      deg_cursor[n] = run;
      run += dn;
    }
  }
  if (tid == 1023) row_ptr[N_NODES] = run;
}

__global__ void scatter_kernel(const int* __restrict__ src,
                               const int* __restrict__ dst,
                               int* __restrict__ cursor,
                               int* __restrict__ esrc) {
  int e = blockIdx.x * blockDim.x + threadIdx.x;
  if (e < N_EDGES) {
    int pos = atomicAdd(&cursor[dst[e]], 1);
    esrc[pos] = src[e];
  }
}

// ===== fused aggregate (post-matmul, 128-d): x[n] = relu( (1+eps)*t[n] + sum t[s] + b ) =====
// one wave per node, lane holds cols 2*lane, 2*lane+1
__global__ __launch_bounds__(256) void gather_kernel(
    const float* __restrict__ t,
    const int* __restrict__ row_ptr,
    const int* __restrict__ esrc,
    const float* __restrict__ epsP, int layer,
    const float* __restrict__ bias,
    float* __restrict__ x)
{
  int wave = (blockIdx.x * blockDim.x + threadIdx.x) >> 6;
  int lane = threadIdx.x & 63;
  if (wave >= N_NODES) return;
  int beg = row_ptr[wave];
  int end = row_ptr[wave + 1];
  float scale = 1.0f + epsP[layer];

  float2 acc = *(const float2*)(t + (size_t)wave * HID + lane * 2);
  acc.x *= scale; acc.y *= scale;
  for (int i = beg; i < end; ++i) {
    int s = esrc[i];
    float2 v = *(const float2*)(t + (size_t)s * HID + lane * 2);
    acc.x += v.x; acc.y += v.y;
  }
  float2 b = *(const float2*)(bias + lane * 2);
  acc.x = fmaxf(acc.x + b.x, 0.0f);
  acc.y = fmaxf(acc.y + b.y, 0.0f);
  *(float2*)(x + (size_t)wave * HID + lane * 2) = acc;
}

// ================= tiled GEMM, N fixed = 128 =================
// C = A@W                      (bias==null)
// C = relu(A@W + bias)         (bias, do_bn=0)
// C = relu(BN(relu(A@W+bias))) (bias, do_bn=1)
__global__ __launch_bounds__(256) void mm_kernel(
    const float* __restrict__ A,
    const float* __restrict__ W,     // K x 128 row-major
    const float* __restrict__ bias,  // 128 or null
    const float* __restrict__ gamma, const float* __restrict__ beta,
    const float* __restrict__ mean,  const float* __restrict__ var,
    float* __restrict__ C,
    int M, int K, int do_bn)
{
  __shared__ float As[BM][BK + 1];
  __shared__ float Ws[BK][HID];

  int tid = threadIdx.x;
  int row0 = blockIdx.x * BM;
  int r  = tid >> 2;     // 0..63
  int cg = tid & 3;      // 0..3
  int row = row0 + r;

  float acc[32];
#pragma unroll
  for (int j = 0; j < 32; ++j) acc[j] = 0.0f;

  for (int kk = 0; kk < K; kk += BK) {
    float4 a = make_float4(0.f, 0.f, 0.f, 0.f);
    if (row < M) a = *(const float4*)(A + (size_t)row * K + kk + cg * 4);
    int kc = cg * 4;
    As[r][kc + 0] = a.x; As[r][kc + 1] = a.y;
    As[r][kc + 2] = a.z; As[r][kc + 3] = a.w;

#pragma unroll
    for (int i = 0; i < 2; ++i) {
      int l = tid + i * 256;
      int wr = l >> 5;
      int wc = (l & 31) * 4;
      float4 w = *(const float4*)(W + (size_t)(kk + wr) * HID + wc);
      *(float4*)&Ws[wr][wc] = w;
    }
    __syncthreads();

#pragma unroll
    for (int k = 0; k < BK; ++k) {
      float av = As[r][k];
#pragma unroll
      for (int j = 0; j < 32; ++j) {
        acc[j] = fmaf(av, Ws[k][cg + 4 * j], acc[j]);
      }
    }
    __syncthreads();
  }

  if (row < M) {
    float* cp = C + (size_t)row * HID;
#pragma unroll
    for (int j = 0; j < 32; ++j) {
      int c = cg + 4 * j;
      float v = acc[j];
      if (bias) {
        v += bias[c];
        v = fmaxf(v, 0.0f);
        if (do_bn) {
          float s = gamma[c] * rsqrtf(var[c] + BN_EPS);
          float t = beta[c] - mean[c] * s;
          v = fmaf(v, s, t);
          v = fmaxf(v, 0.0f);
        }
      }
      cp[c] = v;
    }
  }
}

// ===== fused pair head: out = relu(P1[n0]+P2[n1]+b1) @ w2 + b2 =====
// one wave per pair; lane holds cols 2*lane, 2*lane+1
__global__ __launch_bounds__(256) void pair_kernel(
    const float* __restrict__ P1,   // N_NODES x 128
    const float* __restrict__ P2,   // N_NODES x 128
    const int* __restrict__ ppi,    // NPAIRS x 2
    const int* __restrict__ idx,    // BATCH
    const float* __restrict__ b1,   // 128
    const float* __restrict__ w2,   // 128 x 7
    const float* __restrict__ b2,   // 7
    float* __restrict__ out)        // BATCH x 7
{
  int wave = (blockIdx.x * blockDim.x + threadIdx.x) >> 6;
  int lane = threadIdx.x & 63;
  if (wave >= BATCH) return;

  int pi = idx[wave];
  int n0 = ppi[2 * pi];
  int n1 = ppi[2 * pi + 1];

  float2 p1 = *(const float2*)(P1 + (size_t)n0 * HID + lane * 2);
  float2 p2 = *(const float2*)(P2 + (size_t)n1 * HID + lane * 2);
  float2 bb = *(const float2*)(b1 + lane * 2);
  float vx = fmaxf(p1.x + p2.x + bb.x, 0.0f);
  float vy = fmaxf(p1.y + p2.y + bb.y, 0.0f);

  const float* w2a = w2 + (size_t)(2 * lane) * OUT_DIM;
  const float* w2b = w2 + (size_t)(2 * lane + 1) * OUT_DIM;
#pragma unroll
  for (int o = 0; o < OUT_DIM; ++o) {
    float p = vx * w2a[o] + vy * w2b[o];
#pragma unroll
    for (int s = 32; s > 0; s >>= 1) p += __shfl_down(p, s);
    if (lane == 0) out[(size_t)wave * OUT_DIM + o] = p + b2[o];
  }
}

extern "C" void kernel_launch(void* const* d_in, const int* in_sizes, int n_in,
                              void* d_out, int out_size, void* d_ws, size_t ws_size,
                              hipStream_t stream) {
  const float* feat   = (const float*)d_in[0];
  const int*   src    = (const int*)d_in[1];
  const int*   dst    = (const int*)d_in[2];
  const int*   ppi    = (const int*)d_in[3];
  const int*   idx    = (const int*)d_in[4];
  const float* eps    = (const float*)d_in[5];
  const float* w1_in  = (const float*)d_in[6];
  const float* b1_in  = (const float*)d_in[7];
  const float* w2_in  = (const float*)d_in[8];
  const float* b2_in  = (const float*)d_in[9];
  const float* hw1    = (const float*)d_in[10];
  const float* hb1    = (const float*)d_in[11];
  const float* hw2    = (const float*)d_in[12];
  const float* hb2    = (const float*)d_in[13];
  const float* bng    = (const float*)d_in[14];
  const float* bnb    = (const float*)d_in[15];
  const float* bnm    = (const float*)d_in[16];
  const float* bnv    = (const float*)d_in[17];
  const float* lin_w  = (const float*)d_in[18];
  const float* lin_b  = (const float*)d_in[19];
  const float* int_w1 = (const float*)d_in[20];
  const float* int_b1 = (const float*)d_in[21];
  const float* int_w2 = (const float*)d_in[22];
  const float* int_b2 = (const float*)d_in[23];
  float* out = (float*)d_out;

  const size_t NB = (size_t)N_NODES * HID;  // one node buffer, 25.6 MB
  float* b0 = (float*)d_ws;   // t  / P1
  float* b1 = b0 + NB;        // x  / P2
  float* b2 = b1 + NB;        // h
  float* b3 = b2 + NB;        // hL
  int* row_ptr = (int*)(b3 + NB);          // 50001 (+pad)
  int* cursor  = row_ptr + N_NODES + 8;    // 50000
  int* esrc    = cursor + N_NODES;         // 500000

  int mmBlocks = (N_NODES + BM - 1) / BM;
  int edgeBlocks = (N_EDGES + 255) / 256;
  int nodeWaveBlocks = (N_NODES + 3) / 4;   // 4 waves/block
  int pairWaveBlocks = BATCH / 4;

  // ---- CSR build ----
  hipMemsetAsync(cursor, 0, N_NODES * sizeof(int), stream);
  hist_kernel<<<edgeBlocks, 256, 0, stream>>>(dst, cursor);
  scan_kernel<<<1, 1024, 0, stream>>>(cursor, row_ptr);
  scatter_kernel<<<edgeBlocks, 256, 0, stream>>>(src, dst, cursor, esrc);

  // ---- layer 1: t = feat@w1 (256->128), gather in 128-d, mm2+BN ----
  mm_kernel<<<mmBlocks, 256, 0, stream>>>(feat, w1_in, nullptr,
                                          nullptr, nullptr, nullptr, nullptr,
                                          b0, N_NODES, IN_DIM, 0);
  gather_kernel<<<nodeWaveBlocks, 256, 0, stream>>>(b0, row_ptr, esrc, eps, 0, b1_in, b1);
  mm_kernel<<<mmBlocks, 256, 0, stream>>>(b1, w2_in, b2_in,
                                          bng, bnb, bnm, bnv,
                                          b2, N_NODES, HID, 1);

  // ---- layers 2..3 ----
  for (int l = 1; l < 3; ++l) {
    mm_kernel<<<mmBlocks, 256, 0, stream>>>(b2, hw1 + (size_t)(l - 1) * HID * HID,
                                            nullptr,
                                            nullptr, nullptr, nullptr, nullptr,
                                            b0, N_NODES, HID, 0);
    gather_kernel<<<nodeWaveBlocks, 256, 0, stream>>>(b0, row_ptr, esrc, eps, l,
                                                      hb1 + (size_t)(l - 1) * HID, b1);
    mm_kernel<<<mmBlocks, 256, 0, stream>>>(b1, hw2 + (size_t)(l - 1) * HID * HID,
                                            hb2 + (size_t)(l - 1) * HID,
                                            bng + l * HID, bnb + l * HID,
                                            bnm + l * HID, bnv + l * HID,
                                            b2, N_NODES, HID, 1);
  }

  // ---- lin: hL = relu(h@lin_w + lin_b) ----
  mm_kernel<<<mmBlocks, 256, 0, stream>>>(b2, lin_w, lin_b,
                                          nullptr, nullptr, nullptr, nullptr,
                                          b3, N_NODES, HID, 0);

  // ---- pair head: P1 = hL@W_top, P2 = hL@W_bot, then fused pair kernel ----
  mm_kernel<<<mmBlocks, 256, 0, stream>>>(b3, int_w1, nullptr,
                                          nullptr, nullptr, nullptr, nullptr,
                                          b0, N_NODES, HID, 0);
  mm_kernel<<<mmBlocks, 256, 0, stream>>>(b3, int_w1 + (size_t)HID * HID, nullptr,
                                          nullptr, nullptr, nullptr, nullptr,
                                          b1, N_NODES, HID, 0);
  pair_kernel<<<pairWaveBlocks, 256, 0, stream>>>(b0, b1, ppi, idx,
                                                  int_b1, int_w2, int_b2, out);
}

// Round 10
// 761.156 us; speedup vs baseline: 5.7153x; 1.6656x over previous
//
#include <hip/hip_runtime.h>

#define N_NODES 50000
#define N_EDGES 500000
#define IN_DIM  256
#define HID     128
#define OUT_DIM 7
#define NPAIRS  100000
#define BATCH   65536
#define BN_EPS  1e-5f

typedef __attribute__((ext_vector_type(8))) short bf16x8;   // 8 bf16 = 4 VGPRs
typedef __attribute__((ext_vector_type(4))) float f32x4;

__device__ inline float b2f(ushort u) {
  unsigned int x = ((unsigned int)u) << 16;
  return __uint_as_float(x);
}
__device__ inline ushort f2b(float f) {  // round-to-nearest-even
  unsigned int x = __float_as_uint(f);
  unsigned int r = (x + 0x7fffu + ((x >> 16) & 1u)) >> 16;
  return (ushort)r;
}

// ================= CSR build (once per call) =================
__global__ void hist_kernel(const int* __restrict__ dst, int* __restrict__ deg) {
  int e = blockIdx.x * blockDim.x + threadIdx.x;
  if (e < N_EDGES) atomicAdd(&deg[dst[e]], 1);
}

__global__ __launch_bounds__(1024) void scan_kernel(int* __restrict__ deg_cursor,
                                                    int* __restrict__ row_ptr) {
  __shared__ int partial[1024];
  const int CH = (N_NODES + 1023) / 1024;
  int tid = threadIdx.x;
  int base = tid * CH;

  int sum = 0;
  for (int i = 0; i < CH; ++i) {
    int n = base + i;
    if (n < N_NODES) sum += deg_cursor[n];
  }
  partial[tid] = sum;
  __syncthreads();
  for (int off = 1; off < 1024; off <<= 1) {
    int v = (tid >= off) ? partial[tid - off] : 0;
    __syncthreads();
    partial[tid] += v;
    __syncthreads();
  }
  int run = partial[tid] - sum;
  for (int i = 0; i < CH; ++i) {
    int n = base + i;
    if (n < N_NODES) {
      int dn = deg_cursor[n];
      row_ptr[n] = run;
      deg_cursor[n] = run;
      run += dn;
    }
  }
  if (tid == 1023) row_ptr[N_NODES] = run;
}

__global__ void scatter_kernel(const int* __restrict__ src,
                               const int* __restrict__ dst,
                               int* __restrict__ cursor,
                               int* __restrict__ esrc) {
  int e = blockIdx.x * blockDim.x + threadIdx.x;
  if (e < N_EDGES) {
    int pos = atomicAdd(&cursor[dst[e]], 1);
    esrc[pos] = src[e];
  }
}

// ================= weight convert+transpose: WT[n][k] = bf16(W[k][n]) =================
// slots: 0:w1_in(256x128) 1:w2_in 2:hw1_0 3:hw1_1 4:hw2_0 5:hw2_1 6:lin_w 7:int_w1(256x128)
__global__ void convw_kernel(const float* s0, const float* s1, const float* s2,
                             const float* s3, const float* s4, const float* s5,
                             const float* s6, const float* s7,
                             ushort* d0, ushort* d1, ushort* d2, ushort* d3,
                             ushort* d4, ushort* d5, ushort* d6, ushort* d7) {
  int gid = blockIdx.x * blockDim.x + threadIdx.x;
  const float* srcs[8] = {s0, s1, s2, s3, s4, s5, s6, s7};
  ushort* dsts[8] = {d0, d1, d2, d3, d4, d5, d6, d7};
  const int Ks[8] = {256, 128, 128, 128, 128, 128, 128, 256};
  const int off[9] = {0, 32768, 49152, 65536, 81920, 98304, 114688, 131072, 163840};
  if (gid >= 163840) return;
  int slot = 0;
#pragma unroll
  for (int s = 1; s < 8; ++s) if (gid >= off[s]) slot = s;
  int i = gid - off[slot];
  int K = Ks[slot];
  int k = i >> 7;          // N = 128 always
  int n = i & 127;
  dsts[slot][(size_t)n * K + k] = f2b(srcs[slot][(size_t)k * 128 + n]);
}

// ================= feat fp32 -> bf16 =================
__global__ void convf_kernel(const float* __restrict__ f, ushort* __restrict__ o) {
  int i = blockIdx.x * blockDim.x + threadIdx.x;
  if (i >= N_NODES * IN_DIM / 4) return;
  float4 v = ((const float4*)f)[i];
  ushort4 u;
  u.x = f2b(v.x); u.y = f2b(v.y); u.z = f2b(v.z); u.w = f2b(v.w);
  ((ushort4*)o)[i] = u;
}

// ================= bf16 MFMA GEMM, N fixed = 128 =================
// C = epilogue(A @ W); WT is [128][ldw] bf16 with WT[n][k] = W[k][n]
// epilogue: none (bias=null) / relu(.+bias) / relu(BN(relu(.+bias)))
__global__ __launch_bounds__(256) void mm_bf16(
    const ushort* __restrict__ A,    // M x K bf16
    const ushort* __restrict__ WT,   // 128 x ldw bf16 (transposed)
    const float* __restrict__ bias,
    const float* __restrict__ gamma, const float* __restrict__ beta,
    const float* __restrict__ mean,  const float* __restrict__ var,
    ushort* __restrict__ C,          // M x 128 bf16
    int M, int K, int ldw, int do_bn)
{
  int tid  = threadIdx.x;
  int wid  = tid >> 6;
  int lane = tid & 63;
  int lr = lane & 15;   // A-row / B-col / C-col within tile
  int lg = lane >> 4;   // k-group (0..3)
  int m0 = blockIdx.x * 64 + wid * 16;

  int arow = m0 + lr;
  if (arow >= M) arow = M - 1;           // clamp (stores are guarded)
  const ushort* Ap = A + (size_t)arow * K + lg * 8;

  f32x4 acc[8];
#pragma unroll
  for (int t = 0; t < 8; ++t) acc[t] = (f32x4){0.f, 0.f, 0.f, 0.f};

  for (int kk = 0; kk < K; kk += 32) {
    bf16x8 af = *(const bf16x8*)(Ap + kk);
#pragma unroll
    for (int t = 0; t < 8; ++t) {
      const ushort* Bp = WT + (size_t)(t * 16 + lr) * ldw + kk + lg * 8;
      bf16x8 bf = *(const bf16x8*)Bp;
      acc[t] = __builtin_amdgcn_mfma_f32_16x16x32_bf16(af, bf, acc[t], 0, 0, 0);
    }
  }

#pragma unroll
  for (int t = 0; t < 8; ++t) {
    int c = t * 16 + lr;
    float bs = 0.f, sc = 1.f, sh = 0.f;
    if (bias) bs = bias[c];
    if (do_bn) {
      float s = gamma[c] * rsqrtf(var[c] + BN_EPS);
      sc = s;
      sh = beta[c] - mean[c] * s;
    }
#pragma unroll
    for (int r = 0; r < 4; ++r) {
      int row = m0 + lg * 4 + r;
      if (row < M) {
        float v = acc[t][r];
        if (bias) {
          v += bs;
          v = fmaxf(v, 0.f);
          if (do_bn) { v = fmaf(v, sc, sh); v = fmaxf(v, 0.f); }
        }
        C[(size_t)row * HID + c] = f2b(v);
      }
    }
  }
}

// ===== fused aggregate (bf16): x[n] = relu((1+eps)*t[n] + sum t[s] + b) =====
__global__ __launch_bounds__(256) void gather_kernel(
    const ushort* __restrict__ t,
    const int* __restrict__ row_ptr,
    const int* __restrict__ esrc,
    const float* __restrict__ epsP, int layer,
    const float* __restrict__ bias,
    ushort* __restrict__ x)
{
  int wave = (blockIdx.x * blockDim.x + threadIdx.x) >> 6;
  int lane = threadIdx.x & 63;
  if (wave >= N_NODES) return;
  int beg = row_ptr[wave];
  int end = row_ptr[wave + 1];
  float scale = 1.0f + epsP[layer];

  unsigned int u = *(const unsigned int*)(t + (size_t)wave * HID + lane * 2);
  float ax = b2f((ushort)(u & 0xffff)) * scale;
  float ay = b2f((ushort)(u >> 16)) * scale;
  for (int i = beg; i < end; ++i) {
    int s = esrc[i];
    unsigned int v = *(const unsigned int*)(t + (size_t)s * HID + lane * 2);
    ax += b2f((ushort)(v & 0xffff));
    ay += b2f((ushort)(v >> 16));
  }
  float2 b = *(const float2*)(bias + lane * 2);
  ax = fmaxf(ax + b.x, 0.0f);
  ay = fmaxf(ay + b.y, 0.0f);
  unsigned int o = ((unsigned int)f2b(ay) << 16) | f2b(ax);
  *(unsigned int*)(x + (size_t)wave * HID + lane * 2) = o;
}

// ===== fused pair head: out = relu(P1[n0]+P2[n1]+b1) @ w2 + b2 =====
__global__ __launch_bounds__(256) void pair_kernel(
    const ushort* __restrict__ P1,
    const ushort* __restrict__ P2,
    const int* __restrict__ ppi,
    const int* __restrict__ idx,
    const float* __restrict__ b1,
    const float* __restrict__ w2,   // 128 x 7
    const float* __restrict__ b2,
    float* __restrict__ out)        // BATCH x 7
{
  int wave = (blockIdx.x * blockDim.x + threadIdx.x) >> 6;
  int lane = threadIdx.x & 63;
  if (wave >= BATCH) return;

  int pi = idx[wave];
  int n0 = ppi[2 * pi];
  int n1 = ppi[2 * pi + 1];

  unsigned int u1 = *(const unsigned int*)(P1 + (size_t)n0 * HID + lane * 2);
  unsigned int u2 = *(const unsigned int*)(P2 + (size_t)n1 * HID + lane * 2);
  float2 bb = *(const float2*)(b1 + lane * 2);
  float vx = fmaxf(b2f((ushort)(u1 & 0xffff)) + b2f((ushort)(u2 & 0xffff)) + bb.x, 0.0f);
  float vy = fmaxf(b2f((ushort)(u1 >> 16)) + b2f((ushort)(u2 >> 16)) + bb.y, 0.0f);

  const float* w2a = w2 + (size_t)(2 * lane) * OUT_DIM;
  const float* w2b = w2 + (size_t)(2 * lane + 1) * OUT_DIM;
#pragma unroll
  for (int o = 0; o < OUT_DIM; ++o) {
    float p = vx * w2a[o] + vy * w2b[o];
#pragma unroll
    for (int s = 32; s > 0; s >>= 1) p += __shfl_down(p, s);
    if (lane == 0) out[(size_t)wave * OUT_DIM + o] = p + b2[o];
  }
}

extern "C" void kernel_launch(void* const* d_in, const int* in_sizes, int n_in,
                              void* d_out, int out_size, void* d_ws, size_t ws_size,
                              hipStream_t stream) {
  const float* feat   = (const float*)d_in[0];
  const int*   src    = (const int*)d_in[1];
  const int*   dst    = (const int*)d_in[2];
  const int*   ppi    = (const int*)d_in[3];
  const int*   idx    = (const int*)d_in[4];
  const float* eps    = (const float*)d_in[5];
  const float* w1_in  = (const float*)d_in[6];
  const float* b1_in  = (const float*)d_in[7];
  const float* w2_in  = (const float*)d_in[8];
  const float* b2_in  = (const float*)d_in[9];
  const float* hw1    = (const float*)d_in[10];
  const float* hb1    = (const float*)d_in[11];
  const float* hw2    = (const float*)d_in[12];
  const float* hb2    = (const float*)d_in[13];
  const float* bng    = (const float*)d_in[14];
  const float* bnb    = (const float*)d_in[15];
  const float* bnm    = (const float*)d_in[16];
  const float* bnv    = (const float*)d_in[17];
  const float* lin_w  = (const float*)d_in[18];
  const float* lin_b  = (const float*)d_in[19];
  const float* int_w1 = (const float*)d_in[20];
  const float* int_b1 = (const float*)d_in[21];
  const float* int_w2 = (const float*)d_in[22];
  const float* int_b2 = (const float*)d_in[23];
  float* out = (float*)d_out;

  // ---- workspace layout (16B-aligned blocks) ----
  const size_t NB = (size_t)N_NODES * HID;   // ushort count per node buf
  ushort* featb = (ushort*)d_ws;                        // 50000*256
  ushort* b0 = featb + (size_t)N_NODES * IN_DIM;        // t / P1
  ushort* b1 = b0 + NB;                                 // x / P2
  ushort* b2 = b1 + NB;                                 // h
  ushort* b3 = b2 + NB;                                 // hL
  ushort* WT1  = b3 + NB;          // 128x256
  ushort* WT2  = WT1 + 32768;      // 128x128
  ushort* WH1a = WT2 + 16384;
  ushort* WH1b = WH1a + 16384;
  ushort* WH2a = WH1b + 16384;
  ushort* WH2b = WH2a + 16384;
  ushort* WTL  = WH2b + 16384;
  ushort* WTI  = WTL + 16384;      // 128x256 (int_w1^T)
  int* row_ptr = (int*)(WTI + 32768);
  int* cursor  = row_ptr + N_NODES + 8;
  int* esrc    = cursor + N_NODES;

  int mmBlocks = (N_NODES + 63) / 64;
  int edgeBlocks = (N_EDGES + 255) / 256;
  int nodeWaveBlocks = (N_NODES + 3) / 4;
  int pairWaveBlocks = BATCH / 4;

  // ---- CSR build + weight/feat conversion ----
  hipMemsetAsync(cursor, 0, N_NODES * sizeof(int), stream);
  hist_kernel<<<edgeBlocks, 256, 0, stream>>>(dst, cursor);
  scan_kernel<<<1, 1024, 0, stream>>>(cursor, row_ptr);
  scatter_kernel<<<edgeBlocks, 256, 0, stream>>>(src, dst, cursor, esrc);
  convw_kernel<<<640, 256, 0, stream>>>(w1_in, w2_in, hw1, hw1 + 128 * 128,
                                        hw2, hw2 + 128 * 128, lin_w, int_w1,
                                        WT1, WT2, WH1a, WH1b, WH2a, WH2b, WTL, WTI);
  convf_kernel<<<(N_NODES * IN_DIM / 4 + 255) / 256, 256, 0, stream>>>(feat, featb);

  // ---- layer 1: t = feat@w1 (K=256), gather, mm2+BN ----
  mm_bf16<<<mmBlocks, 256, 0, stream>>>(featb, WT1, nullptr,
                                        nullptr, nullptr, nullptr, nullptr,
                                        b0, N_NODES, IN_DIM, IN_DIM, 0);
  gather_kernel<<<nodeWaveBlocks, 256, 0, stream>>>(b0, row_ptr, esrc, eps, 0, b1_in, b1);
  mm_bf16<<<mmBlocks, 256, 0, stream>>>(b1, WT2, b2_in,
                                        bng, bnb, bnm, bnv,
                                        b2, N_NODES, HID, HID, 1);

  // ---- layers 2..3 ----
  ushort* WH1[2] = {WH1a, WH1b};
  ushort* WH2[2] = {WH2a, WH2b};
  for (int l = 1; l < 3; ++l) {
    mm_bf16<<<mmBlocks, 256, 0, stream>>>(b2, WH1[l - 1], nullptr,
                                          nullptr, nullptr, nullptr, nullptr,
                                          b0, N_NODES, HID, HID, 0);
    gather_kernel<<<nodeWaveBlocks, 256, 0, stream>>>(b0, row_ptr, esrc, eps, l,
                                                      hb1 + (size_t)(l - 1) * HID, b1);
    mm_bf16<<<mmBlocks, 256, 0, stream>>>(b1, WH2[l - 1],
                                          hb2 + (size_t)(l - 1) * HID,
                                          bng + l * HID, bnb + l * HID,
                                          bnm + l * HID, bnv + l * HID,
                                          b2, N_NODES, HID, HID, 1);
  }

  // ---- lin: hL = relu(h@lin_w + lin_b) ----
  mm_bf16<<<mmBlocks, 256, 0, stream>>>(b2, WTL, lin_b,
                                        nullptr, nullptr, nullptr, nullptr,
                                        b3, N_NODES, HID, HID, 0);

  // ---- pair head: P1 = hL@W_top, P2 = hL@W_bot (WTI is [128][256]) ----
  mm_bf16<<<mmBlocks, 256, 0, stream>>>(b3, WTI, nullptr,
                                        nullptr, nullptr, nullptr, nullptr,
                                        b0, N_NODES, HID, IN_DIM, 0);
  mm_bf16<<<mmBlocks, 256, 0, stream>>>(b3, WTI + HID, nullptr,
                                        nullptr, nullptr, nullptr, nullptr,
                                        b1, N_NODES, HID, IN_DIM, 0);
  pair_kernel<<<pairWaveBlocks, 256, 0, stream>>>(b0, b1, ppi, idx,
                                                  int_b1, int_w2, int_b2, out);
}

// Round 11
// 643.779 us; speedup vs baseline: 6.7573x; 1.1823x over previous
//
#include <hip/hip_runtime.h>

#define N_NODES 50000
#define N_EDGES 500000
#define IN_DIM  256
#define HID     128
#define OUT_DIM 7
#define NPAIRS  100000
#define BATCH   65536
#define BN_EPS  1e-5f

#define SCAN_BLK 196   // ceil(50000/256)

typedef __attribute__((ext_vector_type(8))) short bf16x8;   // 8 bf16 = 4 VGPRs
typedef __attribute__((ext_vector_type(4))) float f32x4;

__device__ inline float b2f(ushort u) {
  unsigned int x = ((unsigned int)u) << 16;
  return __uint_as_float(x);
}
__device__ inline ushort f2b(float f) {  // round-to-nearest-even
  unsigned int x = __float_as_uint(f);
  unsigned int r = (x + 0x7fffu + ((x >> 16) & 1u)) >> 16;
  return (ushort)r;
}

// ================= CSR build (once per call) =================
__global__ void hist_kernel(const int* __restrict__ dst, int* __restrict__ deg) {
  int e = blockIdx.x * blockDim.x + threadIdx.x;
  if (e < N_EDGES) atomicAdd(&deg[dst[e]], 1);
}

// ---- multi-block coalesced scan: partial sums ----
__global__ __launch_bounds__(256) void scan_partial(const int* __restrict__ deg,
                                                    int* __restrict__ part) {
  __shared__ int s[256];
  int t = threadIdx.x;
  int i = blockIdx.x * 256 + t;
  s[t] = (i < N_NODES) ? deg[i] : 0;
  __syncthreads();
  for (int off = 128; off > 0; off >>= 1) {
    if (t < off) s[t] += s[t + off];
    __syncthreads();
  }
  if (t == 0) part[blockIdx.x] = s[0];
}

// ---- scan the 196 block partials (1 block) ----
__global__ __launch_bounds__(256) void scan_offsets(int* __restrict__ part) {
  __shared__ int s[256];
  int t = threadIdx.x;
  int v = (t < SCAN_BLK) ? part[t] : 0;
  s[t] = v;
  __syncthreads();
  for (int off = 1; off < 256; off <<= 1) {
    int u = (t >= off) ? s[t - off] : 0;
    __syncthreads();
    s[t] += u;
    __syncthreads();
  }
  if (t < SCAN_BLK) part[t] = s[t] - v;   // exclusive
}

// ---- final: per-block exclusive scan + offset -> row_ptr, cursor ----
// cursor may alias deg (same-thread read-then-write).
__global__ __launch_bounds__(256) void scan_final(const int* __restrict__ deg,
                                                  const int* __restrict__ part,
                                                  int* __restrict__ row_ptr,
                                                  int* __restrict__ cursor) {
  __shared__ int s[256];
  int t = threadIdx.x;
  int i = blockIdx.x * 256 + t;
  int v = (i < N_NODES) ? deg[i] : 0;
  s[t] = v;
  __syncthreads();
  for (int off = 1; off < 256; off <<= 1) {
    int u = (t >= off) ? s[t - off] : 0;
    __syncthreads();
    s[t] += u;
    __syncthreads();
  }
  int excl = s[t] - v + part[blockIdx.x];
  if (i < N_NODES) {
    row_ptr[i] = excl;
    cursor[i] = excl;
    if (i == N_NODES - 1) row_ptr[N_NODES] = excl + v;  // = N_EDGES
  }
}

__global__ void scatter_kernel(const int* __restrict__ src,
                               const int* __restrict__ dst,
                               int* __restrict__ cursor,
                               int* __restrict__ esrc) {
  int e = blockIdx.x * blockDim.x + threadIdx.x;
  if (e < N_EDGES) {
    int pos = atomicAdd(&cursor[dst[e]], 1);
    esrc[pos] = src[e];
  }
}

// ================= weight convert+transpose: WT[n][k] = bf16(W[k][n]) =================
// slots: 0:w1_in(256x128) 1:w2_in 2:hw1_0 3:hw1_1 4:hw2_0 5:hw2_1 6:lin_w 7:int_w1(256x128)
__global__ void convw_kernel(const float* s0, const float* s1, const float* s2,
                             const float* s3, const float* s4, const float* s5,
                             const float* s6, const float* s7,
                             ushort* d0, ushort* d1, ushort* d2, ushort* d3,
                             ushort* d4, ushort* d5, ushort* d6, ushort* d7) {
  int gid = blockIdx.x * blockDim.x + threadIdx.x;
  const float* srcs[8] = {s0, s1, s2, s3, s4, s5, s6, s7};
  ushort* dsts[8] = {d0, d1, d2, d3, d4, d5, d6, d7};
  const int Ks[8] = {256, 128, 128, 128, 128, 128, 128, 256};
  const int off[9] = {0, 32768, 49152, 65536, 81920, 98304, 114688, 131072, 163840};
  if (gid >= 163840) return;
  int slot = 0;
#pragma unroll
  for (int s = 1; s < 8; ++s) if (gid >= off[s]) slot = s;
  int i = gid - off[slot];
  int K = Ks[slot];
  int k = i >> 7;          // N = 128 always
  int n = i & 127;
  dsts[slot][(size_t)n * K + k] = f2b(srcs[slot][(size_t)k * 128 + n]);
}

// ================= feat fp32 -> bf16 =================
__global__ void convf_kernel(const float* __restrict__ f, ushort* __restrict__ o) {
  int i = blockIdx.x * blockDim.x + threadIdx.x;
  if (i >= N_NODES * IN_DIM / 4) return;
  float4 v = ((const float4*)f)[i];
  ushort4 u;
  u.x = f2b(v.x); u.y = f2b(v.y); u.z = f2b(v.z); u.w = f2b(v.w);
  ((ushort4*)o)[i] = u;
}

// ================= bf16 MFMA GEMM, N fixed = 128 =================
// C = epilogue(A @ W); WT is [128][ldw] bf16 with WT[n][k] = W[k][n]
// epilogue: none (bias=null) / relu(.+bias) / relu(BN(relu(.+bias)))
__global__ __launch_bounds__(256) void mm_bf16(
    const ushort* __restrict__ A,    // M x K bf16
    const ushort* __restrict__ WT,   // 128 x ldw bf16 (transposed)
    const float* __restrict__ bias,
    const float* __restrict__ gamma, const float* __restrict__ beta,
    const float* __restrict__ mean,  const float* __restrict__ var,
    ushort* __restrict__ C,          // M x 128 bf16
    int M, int K, int ldw, int do_bn)
{
  int tid  = threadIdx.x;
  int wid  = tid >> 6;
  int lane = tid & 63;
  int lr = lane & 15;   // A-row / B-col / C-col within tile
  int lg = lane >> 4;   // k-group (0..3)
  int m0 = blockIdx.x * 64 + wid * 16;

  int arow = m0 + lr;
  if (arow >= M) arow = M - 1;           // clamp (stores are guarded)
  const ushort* Ap = A + (size_t)arow * K + lg * 8;

  f32x4 acc[8];
#pragma unroll
  for (int t = 0; t < 8; ++t) acc[t] = (f32x4){0.f, 0.f, 0.f, 0.f};

  for (int kk = 0; kk < K; kk += 32) {
    bf16x8 af = *(const bf16x8*)(Ap + kk);
#pragma unroll
    for (int t = 0; t < 8; ++t) {
      const ushort* Bp = WT + (size_t)(t * 16 + lr) * ldw + kk + lg * 8;
      bf16x8 bf = *(const bf16x8*)Bp;
      acc[t] = __builtin_amdgcn_mfma_f32_16x16x32_bf16(af, bf, acc[t], 0, 0, 0);
    }
  }

#pragma unroll
  for (int t = 0; t < 8; ++t) {
    int c = t * 16 + lr;
    float bs = 0.f, sc = 1.f, sh = 0.f;
    if (bias) bs = bias[c];
    if (do_bn) {
      float s = gamma[c] * rsqrtf(var[c] + BN_EPS);
      sc = s;
      sh = beta[c] - mean[c] * s;
    }
#pragma unroll
    for (int r = 0; r < 4; ++r) {
      int row = m0 + lg * 4 + r;
      if (row < M) {
        float v = acc[t][r];
        if (bias) {
          v += bs;
          v = fmaxf(v, 0.f);
          if (do_bn) { v = fmaf(v, sc, sh); v = fmaxf(v, 0.f); }
        }
        C[(size_t)row * HID + c] = f2b(v);
      }
    }
  }
}

// ===== fused aggregate (bf16): x[n] = relu((1+eps)*t[n] + sum t[s] + b) =====
__global__ __launch_bounds__(256) void gather_kernel(
    const ushort* __restrict__ t,
    const int* __restrict__ row_ptr,
    const int* __restrict__ esrc,
    const float* __restrict__ epsP, int layer,
    const float* __restrict__ bias,
    ushort* __restrict__ x)
{
  int wave = (blockIdx.x * blockDim.x + threadIdx.x) >> 6;
  int lane = threadIdx.x & 63;
  if (wave >= N_NODES) return;
  int beg = row_ptr[wave];
  int end = row_ptr[wave + 1];
  float scale = 1.0f + epsP[layer];

  unsigned int u = *(const unsigned int*)(t + (size_t)wave * HID + lane * 2);
  float ax = b2f((ushort)(u & 0xffff)) * scale;
  float ay = b2f((ushort)(u >> 16)) * scale;
  for (int i = beg; i < end; ++i) {
    int s = esrc[i];
    unsigned int v = *(const unsigned int*)(t + (size_t)s * HID + lane * 2);
    ax += b2f((ushort)(v & 0xffff));
    ay += b2f((ushort)(v >> 16));
  }
  float2 b = *(const float2*)(bias + lane * 2);
  ax = fmaxf(ax + b.x, 0.0f);
  ay = fmaxf(ay + b.y, 0.0f);
  unsigned int o = ((unsigned int)f2b(ay) << 16) | f2b(ax);
  *(unsigned int*)(x + (size_t)wave * HID + lane * 2) = o;
}

// ===== fused pair head: out = relu(P1[n0]+P2[n1]+b1) @ w2 + b2 =====
__global__ __launch_bounds__(256) void pair_kernel(
    const ushort* __restrict__ P1,
    const ushort* __restrict__ P2,
    const int* __restrict__ ppi,
    const int* __restrict__ idx,
    const float* __restrict__ b1,
    const float* __restrict__ w2,   // 128 x 7
    const float* __restrict__ b2,
    float* __restrict__ out)        // BATCH x 7
{
  int wave = (blockIdx.x * blockDim.x + threadIdx.x) >> 6;
  int lane = threadIdx.x & 63;
  if (wave >= BATCH) return;

  int pi = idx[wave];
  int n0 = ppi[2 * pi];
  int n1 = ppi[2 * pi + 1];

  unsigned int u1 = *(const unsigned int*)(P1 + (size_t)n0 * HID + lane * 2);
  unsigned int u2 = *(const unsigned int*)(P2 + (size_t)n1 * HID + lane * 2);
  float2 bb = *(const float2*)(b1 + lane * 2);
  float vx = fmaxf(b2f((ushort)(u1 & 0xffff)) + b2f((ushort)(u2 & 0xffff)) + bb.x, 0.0f);
  float vy = fmaxf(b2f((ushort)(u1 >> 16)) + b2f((ushort)(u2 >> 16)) + bb.y, 0.0f);

  const float* w2a = w2 + (size_t)(2 * lane) * OUT_DIM;
  const float* w2b = w2 + (size_t)(2 * lane + 1) * OUT_DIM;
#pragma unroll
  for (int o = 0; o < OUT_DIM; ++o) {
    float p = vx * w2a[o] + vy * w2b[o];
#pragma unroll
    for (int s = 32; s > 0; s >>= 1) p += __shfl_down(p, s);
    if (lane == 0) out[(size_t)wave * OUT_DIM + o] = p + b2[o];
  }
}

extern "C" void kernel_launch(void* const* d_in, const int* in_sizes, int n_in,
                              void* d_out, int out_size, void* d_ws, size_t ws_size,
                              hipStream_t stream) {
  const float* feat   = (const float*)d_in[0];
  const int*   src    = (const int*)d_in[1];
  const int*   dst    = (const int*)d_in[2];
  const int*   ppi    = (const int*)d_in[3];
  const int*   idx    = (const int*)d_in[4];
  const float* eps    = (const float*)d_in[5];
  const float* w1_in  = (const float*)d_in[6];
  const float* b1_in  = (const float*)d_in[7];
  const float* w2_in  = (const float*)d_in[8];
  const float* b2_in  = (const float*)d_in[9];
  const float* hw1    = (const float*)d_in[10];
  const float* hb1    = (const float*)d_in[11];
  const float* hw2    = (const float*)d_in[12];
  const float* hb2    = (const float*)d_in[13];
  const float* bng    = (const float*)d_in[14];
  const float* bnb    = (const float*)d_in[15];
  const float* bnm    = (const float*)d_in[16];
  const float* bnv    = (const float*)d_in[17];
  const float* lin_w  = (const float*)d_in[18];
  const float* lin_b  = (const float*)d_in[19];
  const float* int_w1 = (const float*)d_in[20];
  const float* int_b1 = (const float*)d_in[21];
  const float* int_w2 = (const float*)d_in[22];
  const float* int_b2 = (const float*)d_in[23];
  float* out = (float*)d_out;

  // ---- workspace layout (16B-aligned blocks) ----
  const size_t NB = (size_t)N_NODES * HID;   // ushort count per node buf
  ushort* featb = (ushort*)d_ws;                        // 50000*256
  ushort* b0 = featb + (size_t)N_NODES * IN_DIM;        // t / P1
  ushort* b1 = b0 + NB;                                 // x / P2
  ushort* b2 = b1 + NB;                                 // h
  ushort* b3 = b2 + NB;                                 // hL
  ushort* WT1  = b3 + NB;          // 128x256
  ushort* WT2  = WT1 + 32768;      // 128x128
  ushort* WH1a = WT2 + 16384;
  ushort* WH1b = WH1a + 16384;
  ushort* WH2a = WH1b + 16384;
  ushort* WH2b = WH2a + 16384;
  ushort* WTL  = WH2b + 16384;
  ushort* WTI  = WTL + 16384;      // 128x256 (int_w1^T)
  int* row_ptr = (int*)(WTI + 32768);
  int* cursor  = row_ptr + N_NODES + 8;    // deg, then cursor (aliased)
  int* esrc    = cursor + N_NODES;
  int* part    = esrc + N_EDGES;           // 256 ints

  int mmBlocks = (N_NODES + 63) / 64;
  int edgeBlocks = (N_EDGES + 255) / 256;
  int nodeWaveBlocks = (N_NODES + 3) / 4;
  int pairWaveBlocks = BATCH / 4;

  // ---- CSR build + weight/feat conversion ----
  hipMemsetAsync(cursor, 0, N_NODES * sizeof(int), stream);
  hist_kernel<<<edgeBlocks, 256, 0, stream>>>(dst, cursor);
  scan_partial<<<SCAN_BLK, 256, 0, stream>>>(cursor, part);
  scan_offsets<<<1, 256, 0, stream>>>(part);
  scan_final<<<SCAN_BLK, 256, 0, stream>>>(cursor, part, row_ptr, cursor);
  scatter_kernel<<<edgeBlocks, 256, 0, stream>>>(src, dst, cursor, esrc);
  convw_kernel<<<640, 256, 0, stream>>>(w1_in, w2_in, hw1, hw1 + 128 * 128,
                                        hw2, hw2 + 128 * 128, lin_w, int_w1,
                                        WT1, WT2, WH1a, WH1b, WH2a, WH2b, WTL, WTI);
  convf_kernel<<<(N_NODES * IN_DIM / 4 + 255) / 256, 256, 0, stream>>>(feat, featb);

  // ---- layer 1: t = feat@w1 (K=256), gather, mm2+BN ----
  mm_bf16<<<mmBlocks, 256, 0, stream>>>(featb, WT1, nullptr,
                                        nullptr, nullptr, nullptr, nullptr,
                                        b0, N_NODES, IN_DIM, IN_DIM, 0);
  gather_kernel<<<nodeWaveBlocks, 256, 0, stream>>>(b0, row_ptr, esrc, eps, 0, b1_in, b1);
  mm_bf16<<<mmBlocks, 256, 0, stream>>>(b1, WT2, b2_in,
                                        bng, bnb, bnm, bnv,
                                        b2, N_NODES, HID, HID, 1);

  // ---- layers 2..3 ----
  ushort* WH1[2] = {WH1a, WH1b};
  ushort* WH2[2] = {WH2a, WH2b};
  for (int l = 1; l < 3; ++l) {
    mm_bf16<<<mmBlocks, 256, 0, stream>>>(b2, WH1[l - 1], nullptr,
                                          nullptr, nullptr, nullptr, nullptr,
                                          b0, N_NODES, HID, HID, 0);
    gather_kernel<<<nodeWaveBlocks, 256, 0, stream>>>(b0, row_ptr, esrc, eps, l,
                                                      hb1 + (size_t)(l - 1) * HID, b1);
    mm_bf16<<<mmBlocks, 256, 0, stream>>>(b1, WH2[l - 1],
                                          hb2 + (size_t)(l - 1) * HID,
                                          bng + l * HID, bnb + l * HID,
                                          bnm + l * HID, bnv + l * HID,
                                          b2, N_NODES, HID, HID, 1);
  }

  // ---- lin: hL = relu(h@lin_w + lin_b) ----
  mm_bf16<<<mmBlocks, 256, 0, stream>>>(b2, WTL, lin_b,
                                        nullptr, nullptr, nullptr, nullptr,
                                        b3, N_NODES, HID, HID, 0);

  // ---- pair head: P1 = hL@W_top, P2 = hL@W_bot (WTI is [128][256]) ----
  mm_bf16<<<mmBlocks, 256, 0, stream>>>(b3, WTI, nullptr,
                                        nullptr, nullptr, nullptr, nullptr,
                                        b0, N_NODES, HID, IN_DIM, 0);
  mm_bf16<<<mmBlocks, 256, 0, stream>>>(b3, WTI + HID, nullptr,
                                        nullptr, nullptr, nullptr, nullptr,
                                        b1, N_NODES, HID, IN_DIM, 0);
  pair_kernel<<<pairWaveBlocks, 256, 0, stream>>>(b0, b1, ppi, idx,
                                                  int_b1, int_w2, int_b2, out);
}

// Round 12
// 589.166 us; speedup vs baseline: 7.3837x; 1.0927x over previous
//
#include <hip/hip_runtime.h>

#define N_NODES 50000
#define N_EDGES 500000
#define IN_DIM  256
#define HID     128
#define OUT_DIM 7
#define NPAIRS  100000
#define BATCH   65536
#define BN_EPS  1e-5f

#define SCAN_BLK 196   // ceil(50000/256)

typedef __attribute__((ext_vector_type(8))) short bf16x8;   // 8 bf16 = 4 VGPRs
typedef __attribute__((ext_vector_type(4))) float f32x4;

__device__ inline float b2f(ushort u) {
  unsigned int x = ((unsigned int)u) << 16;
  return __uint_as_float(x);
}
__device__ inline ushort f2b(float f) {  // round-to-nearest-even
  unsigned int x = __float_as_uint(f);
  unsigned int r = (x + 0x7fffu + ((x >> 16) & 1u)) >> 16;
  return (ushort)r;
}

// ================= CSR build (once per call) =================
__global__ void hist_kernel(const int* __restrict__ dst, int* __restrict__ deg) {
  int e = blockIdx.x * blockDim.x + threadIdx.x;
  if (e < N_EDGES) atomicAdd(&deg[dst[e]], 1);
}

__global__ __launch_bounds__(256) void scan_partial(const int* __restrict__ deg,
                                                    int* __restrict__ part) {
  __shared__ int s[256];
  int t = threadIdx.x;
  int i = blockIdx.x * 256 + t;
  s[t] = (i < N_NODES) ? deg[i] : 0;
  __syncthreads();
  for (int off = 128; off > 0; off >>= 1) {
    if (t < off) s[t] += s[t + off];
    __syncthreads();
  }
  if (t == 0) part[blockIdx.x] = s[0];
}

__global__ __launch_bounds__(256) void scan_offsets(int* __restrict__ part) {
  __shared__ int s[256];
  int t = threadIdx.x;
  int v = (t < SCAN_BLK) ? part[t] : 0;
  s[t] = v;
  __syncthreads();
  for (int off = 1; off < 256; off <<= 1) {
    int u = (t >= off) ? s[t - off] : 0;
    __syncthreads();
    s[t] += u;
    __syncthreads();
  }
  if (t < SCAN_BLK) part[t] = s[t] - v;   // exclusive
}

__global__ __launch_bounds__(256) void scan_final(const int* __restrict__ deg,
                                                  const int* __restrict__ part,
                                                  int* __restrict__ row_ptr,
                                                  int* __restrict__ cursor) {
  __shared__ int s[256];
  int t = threadIdx.x;
  int i = blockIdx.x * 256 + t;
  int v = (i < N_NODES) ? deg[i] : 0;
  s[t] = v;
  __syncthreads();
  for (int off = 1; off < 256; off <<= 1) {
    int u = (t >= off) ? s[t - off] : 0;
    __syncthreads();
    s[t] += u;
    __syncthreads();
  }
  int excl = s[t] - v + part[blockIdx.x];
  if (i < N_NODES) {
    row_ptr[i] = excl;
    cursor[i] = excl;
    if (i == N_NODES - 1) row_ptr[N_NODES] = excl + v;  // = N_EDGES
  }
}

__global__ void scatter_kernel(const int* __restrict__ src,
                               const int* __restrict__ dst,
                               int* __restrict__ cursor,
                               int* __restrict__ esrc) {
  int e = blockIdx.x * blockDim.x + threadIdx.x;
  if (e < N_EDGES) {
    int pos = atomicAdd(&cursor[dst[e]], 1);
    esrc[pos] = src[e];
  }
}

// ================= weight convert+transpose: WT[n][k] = bf16(W[k][n]) =================
__global__ void convw_kernel(const float* s0, const float* s1, const float* s2,
                             const float* s3, const float* s4, const float* s5,
                             const float* s6, const float* s7,
                             ushort* d0, ushort* d1, ushort* d2, ushort* d3,
                             ushort* d4, ushort* d5, ushort* d6, ushort* d7) {
  int gid = blockIdx.x * blockDim.x + threadIdx.x;
  const float* srcs[8] = {s0, s1, s2, s3, s4, s5, s6, s7};
  ushort* dsts[8] = {d0, d1, d2, d3, d4, d5, d6, d7};
  const int Ks[8] = {256, 128, 128, 128, 128, 128, 128, 256};
  const int off[9] = {0, 32768, 49152, 65536, 81920, 98304, 114688, 131072, 163840};
  if (gid >= 163840) return;
  int slot = 0;
#pragma unroll
  for (int s = 1; s < 8; ++s) if (gid >= off[s]) slot = s;
  int i = gid - off[slot];
  int K = Ks[slot];
  int k = i >> 7;          // N = 128 always
  int n = i & 127;
  dsts[slot][(size_t)n * K + k] = f2b(srcs[slot][(size_t)k * 128 + n]);
}

// ---- int_w2 (128x7 fp32) -> w2t (16x128 bf16, rows >=7 zero) ----
__global__ void convw2_kernel(const float* __restrict__ w2, ushort* __restrict__ w2t) {
  int gid = blockIdx.x * blockDim.x + threadIdx.x;
  if (gid >= 16 * 128) return;
  int c = gid >> 7;
  int k = gid & 127;
  w2t[gid] = (c < OUT_DIM) ? f2b(w2[(size_t)k * OUT_DIM + c]) : (ushort)0;
}

// ================= bf16 MFMA GEMM (bf16 A), N fixed = 128 =================
__global__ __launch_bounds__(256) void mm_bf16(
    const ushort* __restrict__ A,    // M x K bf16
    const ushort* __restrict__ WT,   // 128 x ldw bf16 (transposed)
    const float* __restrict__ bias,
    const float* __restrict__ gamma, const float* __restrict__ beta,
    const float* __restrict__ mean,  const float* __restrict__ var,
    ushort* __restrict__ C,          // M x 128 bf16
    int M, int K, int ldw, int do_bn)
{
  int tid  = threadIdx.x;
  int wid  = tid >> 6;
  int lane = tid & 63;
  int lr = lane & 15;
  int lg = lane >> 4;
  int m0 = blockIdx.x * 64 + wid * 16;

  int arow = m0 + lr;
  if (arow >= M) arow = M - 1;
  const ushort* Ap = A + (size_t)arow * K + lg * 8;

  f32x4 acc[8];
#pragma unroll
  for (int t = 0; t < 8; ++t) acc[t] = (f32x4){0.f, 0.f, 0.f, 0.f};

  for (int kk = 0; kk < K; kk += 32) {
    bf16x8 af = *(const bf16x8*)(Ap + kk);
#pragma unroll
    for (int t = 0; t < 8; ++t) {
      const ushort* Bp = WT + (size_t)(t * 16 + lr) * ldw + kk + lg * 8;
      bf16x8 bf = *(const bf16x8*)Bp;
      acc[t] = __builtin_amdgcn_mfma_f32_16x16x32_bf16(af, bf, acc[t], 0, 0, 0);
    }
  }

#pragma unroll
  for (int t = 0; t < 8; ++t) {
    int c = t * 16 + lr;
    float bs = 0.f, sc = 1.f, sh = 0.f;
    if (bias) bs = bias[c];
    if (do_bn) {
      float s = gamma[c] * rsqrtf(var[c] + BN_EPS);
      sc = s;
      sh = beta[c] - mean[c] * s;
    }
#pragma unroll
    for (int r = 0; r < 4; ++r) {
      int row = m0 + lg * 4 + r;
      if (row < M) {
        float v = acc[t][r];
        if (bias) {
          v += bs;
          v = fmaxf(v, 0.f);
          if (do_bn) { v = fmaf(v, sc, sh); v = fmaxf(v, 0.f); }
        }
        C[(size_t)row * HID + c] = f2b(v);
      }
    }
  }
}

// ================= bf16 MFMA GEMM with fp32 A (fused convert), for layer 1 =================
__global__ __launch_bounds__(256) void mm_bf16_f32(
    const float* __restrict__ A,     // M x K fp32
    const ushort* __restrict__ WT,   // 128 x K bf16 (transposed)
    ushort* __restrict__ C,          // M x 128 bf16
    int M, int K)
{
  int tid  = threadIdx.x;
  int wid  = tid >> 6;
  int lane = tid & 63;
  int lr = lane & 15;
  int lg = lane >> 4;
  int m0 = blockIdx.x * 64 + wid * 16;

  int arow = m0 + lr;
  if (arow >= M) arow = M - 1;
  const float* Ap = A + (size_t)arow * K + lg * 8;

  f32x4 acc[8];
#pragma unroll
  for (int t = 0; t < 8; ++t) acc[t] = (f32x4){0.f, 0.f, 0.f, 0.f};

  for (int kk = 0; kk < K; kk += 32) {
    float4 a0 = *(const float4*)(Ap + kk);
    float4 a1 = *(const float4*)(Ap + kk + 4);
    bf16x8 af;
    af[0] = (short)f2b(a0.x); af[1] = (short)f2b(a0.y);
    af[2] = (short)f2b(a0.z); af[3] = (short)f2b(a0.w);
    af[4] = (short)f2b(a1.x); af[5] = (short)f2b(a1.y);
    af[6] = (short)f2b(a1.z); af[7] = (short)f2b(a1.w);
#pragma unroll
    for (int t = 0; t < 8; ++t) {
      const ushort* Bp = WT + (size_t)(t * 16 + lr) * K + kk + lg * 8;
      bf16x8 bf = *(const bf16x8*)Bp;
      acc[t] = __builtin_amdgcn_mfma_f32_16x16x32_bf16(af, bf, acc[t], 0, 0, 0);
    }
  }

#pragma unroll
  for (int t = 0; t < 8; ++t) {
    int c = t * 16 + lr;
#pragma unroll
    for (int r = 0; r < 4; ++r) {
      int row = m0 + lg * 4 + r;
      if (row < M) C[(size_t)row * HID + c] = f2b(acc[t][r]);
    }
  }
}

// ===== fused aggregate (bf16): x[n] = relu((1+eps)*t[n] + sum t[s] + b) =====
__global__ __launch_bounds__(256) void gather_kernel(
    const ushort* __restrict__ t,
    const int* __restrict__ row_ptr,
    const int* __restrict__ esrc,
    const float* __restrict__ epsP, int layer,
    const float* __restrict__ bias,
    ushort* __restrict__ x)
{
  int wave = (blockIdx.x * blockDim.x + threadIdx.x) >> 6;
  int lane = threadIdx.x & 63;
  if (wave >= N_NODES) return;
  int beg = row_ptr[wave];
  int end = row_ptr[wave + 1];
  float scale = 1.0f + epsP[layer];

  unsigned int u = *(const unsigned int*)(t + (size_t)wave * HID + lane * 2);
  float ax = b2f((ushort)(u & 0xffff)) * scale;
  float ay = b2f((ushort)(u >> 16)) * scale;
  for (int i = beg; i < end; ++i) {
    int s = esrc[i];
    unsigned int v = *(const unsigned int*)(t + (size_t)s * HID + lane * 2);
    ax += b2f((ushort)(v & 0xffff));
    ay += b2f((ushort)(v >> 16));
  }
  float2 b = *(const float2*)(bias + lane * 2);
  ax = fmaxf(ax + b.x, 0.0f);
  ay = fmaxf(ay + b.y, 0.0f);
  unsigned int o = ((unsigned int)f2b(ay) << 16) | f2b(ax);
  *(unsigned int*)(x + (size_t)wave * HID + lane * 2) = o;
}

// ===== fused MFMA pair head: out = relu(P1[n0]+P2[n1]+b1) @ w2 + b2 =====
// one wave = 16 pairs (one 16x16x32 MFMA tile-column over K=128)
__global__ __launch_bounds__(256) void pair_mfma(
    const ushort* __restrict__ P1,   // N_NODES x 128 bf16
    const ushort* __restrict__ P2,
    const int* __restrict__ ppi,
    const int* __restrict__ idx,
    const float* __restrict__ b1,    // 128 fp32
    const ushort* __restrict__ w2t,  // 16 x 128 bf16 (padded transpose of int_w2)
    const float* __restrict__ b2,    // 7
    float* __restrict__ out)         // BATCH x 7 fp32
{
  int tid  = threadIdx.x;
  int wid  = tid >> 6;
  int lane = tid & 63;
  int lr = lane & 15;   // pair slot within wave / output col
  int lg = lane >> 4;   // k-group
  int p0 = blockIdx.x * 64 + wid * 16;
  int p  = p0 + lr;

  int pi = idx[p];
  int n0 = ppi[2 * pi];
  int n1 = ppi[2 * pi + 1];

  const ushort* r1 = P1 + (size_t)n0 * HID + lg * 8;
  const ushort* r2 = P2 + (size_t)n1 * HID + lg * 8;
  const float*  bp = b1 + lg * 8;
  const ushort* wp = w2t + (size_t)lr * HID + lg * 8;

  f32x4 acc = (f32x4){0.f, 0.f, 0.f, 0.f};
#pragma unroll
  for (int kk = 0; kk < HID; kk += 32) {
    bf16x8 a1v = *(const bf16x8*)(r1 + kk);
    bf16x8 a2v = *(const bf16x8*)(r2 + kk);
    float4 bb0 = *(const float4*)(bp + kk);
    float4 bb1 = *(const float4*)(bp + kk + 4);
    float bbf[8] = {bb0.x, bb0.y, bb0.z, bb0.w, bb1.x, bb1.y, bb1.z, bb1.w};
    bf16x8 af;
#pragma unroll
    for (int j = 0; j < 8; ++j) {
      float v = b2f((ushort)a1v[j]) + b2f((ushort)a2v[j]) + bbf[j];
      af[j] = (short)f2b(fmaxf(v, 0.f));
    }
    bf16x8 bf = *(const bf16x8*)(wp + kk);
    acc = __builtin_amdgcn_mfma_f32_16x16x32_bf16(af, bf, acc, 0, 0, 0);
  }

  if (lr < OUT_DIM) {
    float bias2 = b2[lr];
#pragma unroll
    for (int r = 0; r < 4; ++r) {
      out[(size_t)(p0 + lg * 4 + r) * OUT_DIM + lr] = acc[r] + bias2;
    }
  }
}

extern "C" void kernel_launch(void* const* d_in, const int* in_sizes, int n_in,
                              void* d_out, int out_size, void* d_ws, size_t ws_size,
                              hipStream_t stream) {
  const float* feat   = (const float*)d_in[0];
  const int*   src    = (const int*)d_in[1];
  const int*   dst    = (const int*)d_in[2];
  const int*   ppi    = (const int*)d_in[3];
  const int*   idx    = (const int*)d_in[4];
  const float* eps    = (const float*)d_in[5];
  const float* w1_in  = (const float*)d_in[6];
  const float* b1_in  = (const float*)d_in[7];
  const float* w2_in  = (const float*)d_in[8];
  const float* b2_in  = (const float*)d_in[9];
  const float* hw1    = (const float*)d_in[10];
  const float* hb1    = (const float*)d_in[11];
  const float* hw2    = (const float*)d_in[12];
  const float* hb2    = (const float*)d_in[13];
  const float* bng    = (const float*)d_in[14];
  const float* bnb    = (const float*)d_in[15];
  const float* bnm    = (const float*)d_in[16];
  const float* bnv    = (const float*)d_in[17];
  const float* lin_w  = (const float*)d_in[18];
  const float* lin_b  = (const float*)d_in[19];
  const float* int_w1 = (const float*)d_in[20];
  const float* int_b1 = (const float*)d_in[21];
  const float* int_w2 = (const float*)d_in[22];
  const float* int_b2 = (const float*)d_in[23];
  float* out = (float*)d_out;

  // ---- workspace layout ----
  const size_t NB = (size_t)N_NODES * HID;   // ushort count per node buf
  ushort* b0 = (ushort*)d_ws;      // t / P1
  ushort* b1 = b0 + NB;            // x / P2
  ushort* b2 = b1 + NB;            // h
  ushort* b3 = b2 + NB;            // hL
  ushort* WT1  = b3 + NB;          // 128x256
  ushort* WT2  = WT1 + 32768;      // 128x128
  ushort* WH1a = WT2 + 16384;
  ushort* WH1b = WH1a + 16384;
  ushort* WH2a = WH1b + 16384;
  ushort* WH2b = WH2a + 16384;
  ushort* WTL  = WH2b + 16384;
  ushort* WTI  = WTL + 16384;      // 128x256 (int_w1^T)
  ushort* W2T  = WTI + 32768;      // 16x128 (int_w2^T padded)
  int* row_ptr = (int*)(W2T + 2048);
  int* cursor  = row_ptr + N_NODES + 8;    // deg, then cursor (aliased)
  int* esrc    = cursor + N_NODES;
  int* part    = esrc + N_EDGES;           // 256 ints

  int mmBlocks = (N_NODES + 63) / 64;
  int edgeBlocks = (N_EDGES + 255) / 256;
  int nodeWaveBlocks = (N_NODES + 3) / 4;
  int pairBlocks = BATCH / 64;             // 4 waves x 16 pairs

  // ---- CSR build + weight conversion ----
  hipMemsetAsync(cursor, 0, N_NODES * sizeof(int), stream);
  hist_kernel<<<edgeBlocks, 256, 0, stream>>>(dst, cursor);
  scan_partial<<<SCAN_BLK, 256, 0, stream>>>(cursor, part);
  scan_offsets<<<1, 256, 0, stream>>>(part);
  scan_final<<<SCAN_BLK, 256, 0, stream>>>(cursor, part, row_ptr, cursor);
  scatter_kernel<<<edgeBlocks, 256, 0, stream>>>(src, dst, cursor, esrc);
  convw_kernel<<<640, 256, 0, stream>>>(w1_in, w2_in, hw1, hw1 + 128 * 128,
                                        hw2, hw2 + 128 * 128, lin_w, int_w1,
                                        WT1, WT2, WH1a, WH1b, WH2a, WH2b, WTL, WTI);
  convw2_kernel<<<8, 256, 0, stream>>>(int_w2, W2T);

  // ---- layer 1: t = feat@w1 (K=256, fp32 A fused-convert), gather, mm2+BN ----
  mm_bf16_f32<<<mmBlocks, 256, 0, stream>>>(feat, WT1, b0, N_NODES, IN_DIM);
  gather_kernel<<<nodeWaveBlocks, 256, 0, stream>>>(b0, row_ptr, esrc, eps, 0, b1_in, b1);
  mm_bf16<<<mmBlocks, 256, 0, stream>>>(b1, WT2, b2_in,
                                        bng, bnb, bnm, bnv,
                                        b2, N_NODES, HID, HID, 1);

  // ---- layers 2..3 ----
  ushort* WH1[2] = {WH1a, WH1b};
  ushort* WH2[2] = {WH2a, WH2b};
  for (int l = 1; l < 3; ++l) {
    mm_bf16<<<mmBlocks, 256, 0, stream>>>(b2, WH1[l - 1], nullptr,
                                          nullptr, nullptr, nullptr, nullptr,
                                          b0, N_NODES, HID, HID, 0);
    gather_kernel<<<nodeWaveBlocks, 256, 0, stream>>>(b0, row_ptr, esrc, eps, l,
                                                      hb1 + (size_t)(l - 1) * HID, b1);
    mm_bf16<<<mmBlocks, 256, 0, stream>>>(b1, WH2[l - 1],
                                          hb2 + (size_t)(l - 1) * HID,
                                          bng + l * HID, bnb + l * HID,
                                          bnm + l * HID, bnv + l * HID,
                                          b2, N_NODES, HID, HID, 1);
  }

  // ---- lin: hL = relu(h@lin_w + lin_b) ----
  mm_bf16<<<mmBlocks, 256, 0, stream>>>(b2, WTL, lin_b,
                                        nullptr, nullptr, nullptr, nullptr,
                                        b3, N_NODES, HID, HID, 0);

  // ---- pair head: P1 = hL@W_top, P2 = hL@W_bot, fused MFMA head ----
  mm_bf16<<<mmBlocks, 256, 0, stream>>>(b3, WTI, nullptr,
                                        nullptr, nullptr, nullptr, nullptr,
                                        b0, N_NODES, HID, IN_DIM, 0);
  mm_bf16<<<mmBlocks, 256, 0, stream>>>(b3, WTI + HID, nullptr,
                                        nullptr, nullptr, nullptr, nullptr,
                                        b1, N_NODES, HID, IN_DIM, 0);
  pair_mfma<<<pairBlocks, 256, 0, stream>>>(b0, b1, ppi, idx,
                                            int_b1, W2T, int_b2, out);
}

// Round 13
// 510.502 us; speedup vs baseline: 8.5215x; 1.1541x over previous
//
#include <hip/hip_runtime.h>

#define N_NODES 50000
#define N_EDGES 500000
#define IN_DIM  256
#define HID     128
#define OUT_DIM 7
#define NPAIRS  100000
#define BATCH   65536
#define BN_EPS  1e-5f

#define SCAN_BLK 196   // ceil(50000/256)

typedef __attribute__((ext_vector_type(8))) short bf16x8;   // 8 bf16 = 4 VGPRs
typedef __attribute__((ext_vector_type(4))) float f32x4;

__device__ inline float b2f(ushort u) {
  unsigned int x = ((unsigned int)u) << 16;
  return __uint_as_float(x);
}
__device__ inline ushort f2b(float f) {  // round-to-nearest-even
  unsigned int x = __float_as_uint(f);
  unsigned int r = (x + 0x7fffu + ((x >> 16) & 1u)) >> 16;
  return (ushort)r;
}

// ================= CSR build (once per call) =================
__global__ void hist_kernel(const int* __restrict__ dst, int* __restrict__ deg) {
  int e = blockIdx.x * blockDim.x + threadIdx.x;
  if (e < N_EDGES) atomicAdd(&deg[dst[e]], 1);
}

__global__ __launch_bounds__(256) void scan_partial(const int* __restrict__ deg,
                                                    int* __restrict__ part) {
  __shared__ int s[256];
  int t = threadIdx.x;
  int i = blockIdx.x * 256 + t;
  s[t] = (i < N_NODES) ? deg[i] : 0;
  __syncthreads();
  for (int off = 128; off > 0; off >>= 1) {
    if (t < off) s[t] += s[t + off];
    __syncthreads();
  }
  if (t == 0) part[blockIdx.x] = s[0];
}

__global__ __launch_bounds__(256) void scan_offsets(int* __restrict__ part) {
  __shared__ int s[256];
  int t = threadIdx.x;
  int v = (t < SCAN_BLK) ? part[t] : 0;
  s[t] = v;
  __syncthreads();
  for (int off = 1; off < 256; off <<= 1) {
    int u = (t >= off) ? s[t - off] : 0;
    __syncthreads();
    s[t] += u;
    __syncthreads();
  }
  if (t < SCAN_BLK) part[t] = s[t] - v;   // exclusive
}

__global__ __launch_bounds__(256) void scan_final(const int* __restrict__ deg,
                                                  const int* __restrict__ part,
                                                  int* __restrict__ row_ptr,
                                                  int* __restrict__ cursor) {
  __shared__ int s[256];
  int t = threadIdx.x;
  int i = blockIdx.x * 256 + t;
  int v = (i < N_NODES) ? deg[i] : 0;
  s[t] = v;
  __syncthreads();
  for (int off = 1; off < 256; off <<= 1) {
    int u = (t >= off) ? s[t - off] : 0;
    __syncthreads();
    s[t] += u;
    __syncthreads();
  }
  int excl = s[t] - v + part[blockIdx.x];
  if (i < N_NODES) {
    row_ptr[i] = excl;
    cursor[i] = excl;
    if (i == N_NODES - 1) row_ptr[N_NODES] = excl + v;  // = N_EDGES
  }
}

__global__ void scatter_kernel(const int* __restrict__ src,
                               const int* __restrict__ dst,
                               int* __restrict__ cursor,
                               int* __restrict__ esrc) {
  int e = blockIdx.x * blockDim.x + threadIdx.x;
  if (e < N_EDGES) {
    int pos = atomicAdd(&cursor[dst[e]], 1);
    esrc[pos] = src[e];
  }
}

// ================= weight convert+transpose: WT[n][k] = bf16(W[k][n]) =================
__global__ void convw_kernel(const float* s0, const float* s1, const float* s2,
                             const float* s3, const float* s4, const float* s5,
                             const float* s6, const float* s7,
                             ushort* d0, ushort* d1, ushort* d2, ushort* d3,
                             ushort* d4, ushort* d5, ushort* d6, ushort* d7) {
  int gid = blockIdx.x * blockDim.x + threadIdx.x;
  const float* srcs[8] = {s0, s1, s2, s3, s4, s5, s6, s7};
  ushort* dsts[8] = {d0, d1, d2, d3, d4, d5, d6, d7};
  const int Ks[8] = {256, 128, 128, 128, 128, 128, 128, 256};
  const int off[9] = {0, 32768, 49152, 65536, 81920, 98304, 114688, 131072, 163840};
  if (gid >= 163840) return;
  int slot = 0;
#pragma unroll
  for (int s = 1; s < 8; ++s) if (gid >= off[s]) slot = s;
  int i = gid - off[slot];
  int K = Ks[slot];
  int k = i >> 7;          // N = 128 always
  int n = i & 127;
  dsts[slot][(size_t)n * K + k] = f2b(srcs[slot][(size_t)k * 128 + n]);
}

// ---- int_w2 (128x7 fp32) -> w2t (16x128 bf16, rows >=7 zero) ----
__global__ void convw2_kernel(const float* __restrict__ w2, ushort* __restrict__ w2t) {
  int gid = blockIdx.x * blockDim.x + threadIdx.x;
  if (gid >= 16 * 128) return;
  int c = gid >> 7;
  int k = gid & 127;
  w2t[gid] = (c < OUT_DIM) ? f2b(w2[(size_t)k * OUT_DIM + c]) : (ushort)0;
}

// ================= bf16 MFMA GEMM (bf16 A), N fixed = 128 =================
__global__ __launch_bounds__(256) void mm_bf16(
    const ushort* __restrict__ A,    // M x K bf16
    const ushort* __restrict__ WT,   // 128 x ldw bf16 (transposed)
    const float* __restrict__ bias,
    const float* __restrict__ gamma, const float* __restrict__ beta,
    const float* __restrict__ mean,  const float* __restrict__ var,
    ushort* __restrict__ C,          // M x 128 bf16
    int M, int K, int ldw, int do_bn)
{
  int tid  = threadIdx.x;
  int wid  = tid >> 6;
  int lane = tid & 63;
  int lr = lane & 15;
  int lg = lane >> 4;
  int m0 = blockIdx.x * 64 + wid * 16;

  int arow = m0 + lr;
  if (arow >= M) arow = M - 1;
  const ushort* Ap = A + (size_t)arow * K + lg * 8;

  f32x4 acc[8];
#pragma unroll
  for (int t = 0; t < 8; ++t) acc[t] = (f32x4){0.f, 0.f, 0.f, 0.f};

  for (int kk = 0; kk < K; kk += 32) {
    bf16x8 af = *(const bf16x8*)(Ap + kk);
#pragma unroll
    for (int t = 0; t < 8; ++t) {
      const ushort* Bp = WT + (size_t)(t * 16 + lr) * ldw + kk + lg * 8;
      bf16x8 bf = *(const bf16x8*)Bp;
      acc[t] = __builtin_amdgcn_mfma_f32_16x16x32_bf16(af, bf, acc[t], 0, 0, 0);
    }
  }

#pragma unroll
  for (int t = 0; t < 8; ++t) {
    int c = t * 16 + lr;
    float bs = 0.f, sc = 1.f, sh = 0.f;
    if (bias) bs = bias[c];
    if (do_bn) {
      float s = gamma[c] * rsqrtf(var[c] + BN_EPS);
      sc = s;
      sh = beta[c] - mean[c] * s;
    }
#pragma unroll
    for (int r = 0; r < 4; ++r) {
      int row = m0 + lg * 4 + r;
      if (row < M) {
        float v = acc[t][r];
        if (bias) {
          v += bs;
          v = fmaxf(v, 0.f);
          if (do_bn) { v = fmaf(v, sc, sh); v = fmaxf(v, 0.f); }
        }
        C[(size_t)row * HID + c] = f2b(v);
      }
    }
  }
}

// ===== dual GEMM for pair head: C0 = A@W_top, C1 = A@W_bot (one A pass) =====
// WT is int_w1^T laid out [128][256]: row n, col k -> int_w1[k][n]
__global__ __launch_bounds__(256) void mm_bf16_dual(
    const ushort* __restrict__ A,    // M x 128 bf16
    const ushort* __restrict__ WT,   // 128 x 256 bf16
    ushort* __restrict__ C0,
    ushort* __restrict__ C1,
    int M)
{
  int tid  = threadIdx.x;
  int wid  = tid >> 6;
  int lane = tid & 63;
  int lr = lane & 15;
  int lg = lane >> 4;
  int m0 = blockIdx.x * 64 + wid * 16;

  int arow = m0 + lr;
  if (arow >= M) arow = M - 1;
  const ushort* Ap = A + (size_t)arow * HID + lg * 8;

  f32x4 acc[16];
#pragma unroll
  for (int t = 0; t < 16; ++t) acc[t] = (f32x4){0.f, 0.f, 0.f, 0.f};

  for (int kk = 0; kk < HID; kk += 32) {
    bf16x8 af = *(const bf16x8*)(Ap + kk);
#pragma unroll
    for (int t = 0; t < 16; ++t) {
      int half = t >> 3;                  // 0: W_top (k<128), 1: W_bot (k>=128)
      int nrow = (t & 7) * 16 + lr;
      const ushort* Bp = WT + (size_t)nrow * 256 + half * 128 + kk + lg * 8;
      bf16x8 bf = *(const bf16x8*)Bp;
      acc[t] = __builtin_amdgcn_mfma_f32_16x16x32_bf16(af, bf, acc[t], 0, 0, 0);
    }
  }

#pragma unroll
  for (int t = 0; t < 16; ++t) {
    int c = (t & 7) * 16 + lr;
    ushort* C = (t < 8) ? C0 : C1;
#pragma unroll
    for (int r = 0; r < 4; ++r) {
      int row = m0 + lg * 4 + r;
      if (row < M) C[(size_t)row * HID + c] = f2b(acc[t][r]);
    }
  }
}

// ================= bf16 MFMA GEMM with fp32 A (fused convert), for layer 1 =================
__global__ __launch_bounds__(256) void mm_bf16_f32(
    const float* __restrict__ A,     // M x K fp32
    const ushort* __restrict__ WT,   // 128 x K bf16 (transposed)
    ushort* __restrict__ C,          // M x 128 bf16
    int M, int K)
{
  int tid  = threadIdx.x;
  int wid  = tid >> 6;
  int lane = tid & 63;
  int lr = lane & 15;
  int lg = lane >> 4;
  int m0 = blockIdx.x * 64 + wid * 16;

  int arow = m0 + lr;
  if (arow >= M) arow = M - 1;
  const float* Ap = A + (size_t)arow * K + lg * 8;

  f32x4 acc[8];
#pragma unroll
  for (int t = 0; t < 8; ++t) acc[t] = (f32x4){0.f, 0.f, 0.f, 0.f};

  for (int kk = 0; kk < K; kk += 32) {
    float4 a0 = *(const float4*)(Ap + kk);
    float4 a1 = *(const float4*)(Ap + kk + 4);
    bf16x8 af;
    af[0] = (short)f2b(a0.x); af[1] = (short)f2b(a0.y);
    af[2] = (short)f2b(a0.z); af[3] = (short)f2b(a0.w);
    af[4] = (short)f2b(a1.x); af[5] = (short)f2b(a1.y);
    af[6] = (short)f2b(a1.z); af[7] = (short)f2b(a1.w);
#pragma unroll
    for (int t = 0; t < 8; ++t) {
      const ushort* Bp = WT + (size_t)(t * 16 + lr) * K + kk + lg * 8;
      bf16x8 bf = *(const bf16x8*)Bp;
      acc[t] = __builtin_amdgcn_mfma_f32_16x16x32_bf16(af, bf, acc[t], 0, 0, 0);
    }
  }

#pragma unroll
  for (int t = 0; t < 8; ++t) {
    int c = t * 16 + lr;
#pragma unroll
    for (int r = 0; r < 4; ++r) {
      int row = m0 + lg * 4 + r;
      if (row < M) C[(size_t)row * HID + c] = f2b(acc[t][r]);
    }
  }
}

// ===== fused aggregate (bf16), 4-way unrolled for MLP =====
// x[n] = relu((1+eps)*t[n] + sum t[s] + b)
__global__ __launch_bounds__(256) void gather_kernel(
    const ushort* __restrict__ t,
    const int* __restrict__ row_ptr,
    const int* __restrict__ esrc,
    const float* __restrict__ epsP, int layer,
    const float* __restrict__ bias,
    ushort* __restrict__ x)
{
  int wave = (blockIdx.x * blockDim.x + threadIdx.x) >> 6;
  int lane = threadIdx.x & 63;
  if (wave >= N_NODES) return;
  int beg = row_ptr[wave];
  int end = row_ptr[wave + 1];
  float scale = 1.0f + epsP[layer];

  unsigned int u = *(const unsigned int*)(t + (size_t)wave * HID + lane * 2);
  float ax = b2f((ushort)(u & 0xffff)) * scale;
  float ay = b2f((ushort)(u >> 16)) * scale;

  int i = beg;
  for (; i + 4 <= end; i += 4) {
    int s0 = esrc[i + 0];
    int s1 = esrc[i + 1];
    int s2 = esrc[i + 2];
    int s3 = esrc[i + 3];
    unsigned int v0 = *(const unsigned int*)(t + (size_t)s0 * HID + lane * 2);
    unsigned int v1 = *(const unsigned int*)(t + (size_t)s1 * HID + lane * 2);
    unsigned int v2 = *(const unsigned int*)(t + (size_t)s2 * HID + lane * 2);
    unsigned int v3 = *(const unsigned int*)(t + (size_t)s3 * HID + lane * 2);
    ax += b2f((ushort)(v0 & 0xffff)) + b2f((ushort)(v1 & 0xffff)) +
          b2f((ushort)(v2 & 0xffff)) + b2f((ushort)(v3 & 0xffff));
    ay += b2f((ushort)(v0 >> 16)) + b2f((ushort)(v1 >> 16)) +
          b2f((ushort)(v2 >> 16)) + b2f((ushort)(v3 >> 16));
  }
  for (; i < end; ++i) {
    int s = esrc[i];
    unsigned int v = *(const unsigned int*)(t + (size_t)s * HID + lane * 2);
    ax += b2f((ushort)(v & 0xffff));
    ay += b2f((ushort)(v >> 16));
  }

  float2 b = *(const float2*)(bias + lane * 2);
  ax = fmaxf(ax + b.x, 0.0f);
  ay = fmaxf(ay + b.y, 0.0f);
  unsigned int o = ((unsigned int)f2b(ay) << 16) | f2b(ax);
  *(unsigned int*)(x + (size_t)wave * HID + lane * 2) = o;
}

// ===== fused MFMA pair head: out = relu(P1[n0]+P2[n1]+b1) @ w2 + b2 =====
__global__ __launch_bounds__(256) void pair_mfma(
    const ushort* __restrict__ P1,   // N_NODES x 128 bf16
    const ushort* __restrict__ P2,
    const int* __restrict__ ppi,
    const int* __restrict__ idx,
    const float* __restrict__ b1,    // 128 fp32
    const ushort* __restrict__ w2t,  // 16 x 128 bf16 (padded transpose of int_w2)
    const float* __restrict__ b2,    // 7
    float* __restrict__ out)         // BATCH x 7 fp32
{
  int tid  = threadIdx.x;
  int wid  = tid >> 6;
  int lane = tid & 63;
  int lr = lane & 15;
  int lg = lane >> 4;
  int p0 = blockIdx.x * 64 + wid * 16;
  int p  = p0 + lr;

  int pi = idx[p];
  int n0 = ppi[2 * pi];
  int n1 = ppi[2 * pi + 1];

  const ushort* r1 = P1 + (size_t)n0 * HID + lg * 8;
  const ushort* r2 = P2 + (size_t)n1 * HID + lg * 8;
  const float*  bp = b1 + lg * 8;
  const ushort* wp = w2t + (size_t)lr * HID + lg * 8;

  f32x4 acc = (f32x4){0.f, 0.f, 0.f, 0.f};
#pragma unroll
  for (int kk = 0; kk < HID; kk += 32) {
    bf16x8 a1v = *(const bf16x8*)(r1 + kk);
    bf16x8 a2v = *(const bf16x8*)(r2 + kk);
    float4 bb0 = *(const float4*)(bp + kk);
    float4 bb1 = *(const float4*)(bp + kk + 4);
    float bbf[8] = {bb0.x, bb0.y, bb0.z, bb0.w, bb1.x, bb1.y, bb1.z, bb1.w};
    bf16x8 af;
#pragma unroll
    for (int j = 0; j < 8; ++j) {
      float v = b2f((ushort)a1v[j]) + b2f((ushort)a2v[j]) + bbf[j];
      af[j] = (short)f2b(fmaxf(v, 0.f));
    }
    bf16x8 bf = *(const bf16x8*)(wp + kk);
    acc = __builtin_amdgcn_mfma_f32_16x16x32_bf16(af, bf, acc, 0, 0, 0);
  }

  if (lr < OUT_DIM) {
    float bias2 = b2[lr];
#pragma unroll
    for (int r = 0; r < 4; ++r) {
      out[(size_t)(p0 + lg * 4 + r) * OUT_DIM + lr] = acc[r] + bias2;
    }
  }
}

extern "C" void kernel_launch(void* const* d_in, const int* in_sizes, int n_in,
                              void* d_out, int out_size, void* d_ws, size_t ws_size,
                              hipStream_t stream) {
  const float* feat   = (const float*)d_in[0];
  const int*   src    = (const int*)d_in[1];
  const int*   dst    = (const int*)d_in[2];
  const int*   ppi    = (const int*)d_in[3];
  const int*   idx    = (const int*)d_in[4];
  const float* eps    = (const float*)d_in[5];
  const float* w1_in  = (const float*)d_in[6];
  const float* b1_in  = (const float*)d_in[7];
  const float* w2_in  = (const float*)d_in[8];
  const float* b2_in  = (const float*)d_in[9];
  const float* hw1    = (const float*)d_in[10];
  const float* hb1    = (const float*)d_in[11];
  const float* hw2    = (const float*)d_in[12];
  const float* hb2    = (const float*)d_in[13];
  const float* bng    = (const float*)d_in[14];
  const float* bnb    = (const float*)d_in[15];
  const float* bnm    = (const float*)d_in[16];
  const float* bnv    = (const float*)d_in[17];
  const float* lin_w  = (const float*)d_in[18];
  const float* lin_b  = (const float*)d_in[19];
  const float* int_w1 = (const float*)d_in[20];
  const float* int_b1 = (const float*)d_in[21];
  const float* int_w2 = (const float*)d_in[22];
  const float* int_b2 = (const float*)d_in[23];
  float* out = (float*)d_out;

  // ---- workspace layout ----
  const size_t NB = (size_t)N_NODES * HID;   // ushort count per node buf
  ushort* b0 = (ushort*)d_ws;      // t / P1
  ushort* b1 = b0 + NB;            // x / P2
  ushort* b2 = b1 + NB;            // h
  ushort* b3 = b2 + NB;            // hL
  ushort* WT1  = b3 + NB;          // 128x256
  ushort* WT2  = WT1 + 32768;      // 128x128
  ushort* WH1a = WT2 + 16384;
  ushort* WH1b = WH1a + 16384;
  ushort* WH2a = WH1b + 16384;
  ushort* WH2b = WH2a + 16384;
  ushort* WTL  = WH2b + 16384;
  ushort* WTI  = WTL + 16384;      // 128x256 (int_w1^T)
  ushort* W2T  = WTI + 32768;      // 16x128 (int_w2^T padded)
  int* row_ptr = (int*)(W2T + 2048);
  int* cursor  = row_ptr + N_NODES + 8;    // deg, then cursor (aliased)
  int* esrc    = cursor + N_NODES;
  int* part    = esrc + N_EDGES;           // 256 ints

  int mmBlocks = (N_NODES + 63) / 64;
  int edgeBlocks = (N_EDGES + 255) / 256;
  int nodeWaveBlocks = (N_NODES + 3) / 4;
  int pairBlocks = BATCH / 64;             // 4 waves x 16 pairs

  // ---- CSR build + weight conversion ----
  hipMemsetAsync(cursor, 0, N_NODES * sizeof(int), stream);
  hist_kernel<<<edgeBlocks, 256, 0, stream>>>(dst, cursor);
  scan_partial<<<SCAN_BLK, 256, 0, stream>>>(cursor, part);
  scan_offsets<<<1, 256, 0, stream>>>(part);
  scan_final<<<SCAN_BLK, 256, 0, stream>>>(cursor, part, row_ptr, cursor);
  scatter_kernel<<<edgeBlocks, 256, 0, stream>>>(src, dst, cursor, esrc);
  convw_kernel<<<640, 256, 0, stream>>>(w1_in, w2_in, hw1, hw1 + 128 * 128,
                                        hw2, hw2 + 128 * 128, lin_w, int_w1,
                                        WT1, WT2, WH1a, WH1b, WH2a, WH2b, WTL, WTI);
  convw2_kernel<<<8, 256, 0, stream>>>(int_w2, W2T);

  // ---- layer 1: t = feat@w1 (K=256, fp32 A fused-convert), gather, mm2+BN ----
  mm_bf16_f32<<<mmBlocks, 256, 0, stream>>>(feat, WT1, b0, N_NODES, IN_DIM);
  gather_kernel<<<nodeWaveBlocks, 256, 0, stream>>>(b0, row_ptr, esrc, eps, 0, b1_in, b1);
  mm_bf16<<<mmBlocks, 256, 0, stream>>>(b1, WT2, b2_in,
                                        bng, bnb, bnm, bnv,
                                        b2, N_NODES, HID, HID, 1);

  // ---- layers 2..3 ----
  ushort* WH1[2] = {WH1a, WH1b};
  ushort* WH2[2] = {WH2a, WH2b};
  for (int l = 1; l < 3; ++l) {
    mm_bf16<<<mmBlocks, 256, 0, stream>>>(b2, WH1[l - 1], nullptr,
                                          nullptr, nullptr, nullptr, nullptr,
                                          b0, N_NODES, HID, HID, 0);
    gather_kernel<<<nodeWaveBlocks, 256, 0, stream>>>(b0, row_ptr, esrc, eps, l,
                                                      hb1 + (size_t)(l - 1) * HID, b1);
    mm_bf16<<<mmBlocks, 256, 0, stream>>>(b1, WH2[l - 1],
                                          hb2 + (size_t)(l - 1) * HID,
                                          bng + l * HID, bnb + l * HID,
                                          bnm + l * HID, bnv + l * HID,
                                          b2, N_NODES, HID, HID, 1);
  }

  // ---- lin: hL = relu(h@lin_w + lin_b) ----
  mm_bf16<<<mmBlocks, 256, 0, stream>>>(b2, WTL, lin_b,
                                        nullptr, nullptr, nullptr, nullptr,
                                        b3, N_NODES, HID, HID, 0);

  // ---- pair head: P1,P2 in one pass, then fused MFMA head ----
  mm_bf16_dual<<<mmBlocks, 256, 0, stream>>>(b3, WTI, b0, b1, N_NODES);
  pair_mfma<<<pairBlocks, 256, 0, stream>>>(b0, b1, ppi, idx,
                                            int_b1, W2T, int_b2, out);
}

// Round 16
// 494.163 us; speedup vs baseline: 8.8032x; 1.0331x over previous
//
#include <hip/hip_runtime.h>

#define N_NODES 50000
#define N_EDGES 500000
#define IN_DIM  256
#define HID     128
#define OUT_DIM 7
#define NPAIRS  100000
#define BATCH   65536
#define BN_EPS  1e-5f

#define SCAN_BLK 196   // ceil(50000/256)

typedef __attribute__((ext_vector_type(8))) short bf16x8;   // 8 bf16 = 4 VGPRs
typedef __attribute__((ext_vector_type(4))) float f32x4;

__device__ inline float b2f(ushort u) {
  unsigned int x = ((unsigned int)u) << 16;
  return __uint_as_float(x);
}
__device__ inline ushort f2b(float f) {  // round-to-nearest-even
  unsigned int x = __float_as_uint(f);
  unsigned int r = (x + 0x7fffu + ((x >> 16) & 1u)) >> 16;
  return (ushort)r;
}

// ================= CSR build (once per call) =================
__global__ void hist_kernel(const int* __restrict__ dst, int* __restrict__ deg) {
  int e = blockIdx.x * blockDim.x + threadIdx.x;
  if (e < N_EDGES) atomicAdd(&deg[dst[e]], 1);
}

__global__ __launch_bounds__(256) void scan_partial(const int* __restrict__ deg,
                                                    int* __restrict__ part) {
  __shared__ int s[256];
  int t = threadIdx.x;
  int i = blockIdx.x * 256 + t;
  s[t] = (i < N_NODES) ? deg[i] : 0;
  __syncthreads();
  for (int off = 128; off > 0; off >>= 1) {
    if (t < off) s[t] += s[t + off];
    __syncthreads();
  }
  if (t == 0) part[blockIdx.x] = s[0];
}

__global__ __launch_bounds__(256) void scan_offsets(int* __restrict__ part) {
  __shared__ int s[256];
  int t = threadIdx.x;
  int v = (t < SCAN_BLK) ? part[t] : 0;
  s[t] = v;
  __syncthreads();
  for (int off = 1; off < 256; off <<= 1) {
    int u = (t >= off) ? s[t - off] : 0;
    __syncthreads();
    s[t] += u;
    __syncthreads();
  }
  if (t < SCAN_BLK) part[t] = s[t] - v;   // exclusive
}

__global__ __launch_bounds__(256) void scan_final(const int* __restrict__ deg,
                                                  const int* __restrict__ part,
                                                  int* __restrict__ row_ptr,
                                                  int* __restrict__ cursor) {
  __shared__ int s[256];
  int t = threadIdx.x;
  int i = blockIdx.x * 256 + t;
  int v = (i < N_NODES) ? deg[i] : 0;
  s[t] = v;
  __syncthreads();
  for (int off = 1; off < 256; off <<= 1) {
    int u = (t >= off) ? s[t - off] : 0;
    __syncthreads();
    s[t] += u;
    __syncthreads();
  }
  int excl = s[t] - v + part[blockIdx.x];
  if (i < N_NODES) {
    row_ptr[i] = excl;
    cursor[i] = excl;
    if (i == N_NODES - 1) row_ptr[N_NODES] = excl + v;  // = N_EDGES
  }
}

__global__ void scatter_kernel(const int* __restrict__ src,
                               const int* __restrict__ dst,
                               int* __restrict__ cursor,
                               int* __restrict__ esrc) {
  int e = blockIdx.x * blockDim.x + threadIdx.x;
  if (e < N_EDGES) {
    int pos = atomicAdd(&cursor[dst[e]], 1);
    esrc[pos] = src[e];
  }
}

// ================= weight convert+transpose: WT[n][k] = bf16(W[k][n]) =================
__global__ void convw_kernel(const float* s0, const float* s1, const float* s2,
                             const float* s3, const float* s4, const float* s5,
                             const float* s6, const float* s7,
                             ushort* d0, ushort* d1, ushort* d2, ushort* d3,
                             ushort* d4, ushort* d5, ushort* d6, ushort* d7) {
  int gid = blockIdx.x * blockDim.x + threadIdx.x;
  const float* srcs[8] = {s0, s1, s2, s3, s4, s5, s6, s7};
  ushort* dsts[8] = {d0, d1, d2, d3, d4, d5, d6, d7};
  const int Ks[8] = {256, 128, 128, 128, 128, 128, 128, 256};
  const int off[9] = {0, 32768, 49152, 65536, 81920, 98304, 114688, 131072, 163840};
  if (gid >= 163840) return;
  int slot = 0;
#pragma unroll
  for (int s = 1; s < 8; ++s) if (gid >= off[s]) slot = s;
  int i = gid - off[slot];
  int K = Ks[slot];
  int k = i >> 7;          // N = 128 always
  int n = i & 127;
  dsts[slot][(size_t)n * K + k] = f2b(srcs[slot][(size_t)k * 128 + n]);
}

// ---- int_w2 (128x7 fp32) -> w2t (16x128 bf16, rows >=7 zero) ----
__global__ void convw2_kernel(const float* __restrict__ w2, ushort* __restrict__ w2t) {
  int gid = blockIdx.x * blockDim.x + threadIdx.x;
  if (gid >= 16 * 128) return;
  int c = gid >> 7;
  int k = gid & 127;
  w2t[gid] = (c < OUT_DIM) ? f2b(w2[(size_t)k * OUT_DIM + c]) : (ushort)0;
}

// ================= bf16 MFMA GEMM (bf16 A), N=128, K templated =================
// wave = 16 rows x 64 cols (4 tiles); block = 4 waves = 32 rows x 128 cols
template <int K>
__global__ __launch_bounds__(256) void mm_bf16_t(
    const ushort* __restrict__ A,    // M x K bf16
    const ushort* __restrict__ WT,   // 128 x K bf16 (transposed)
    const float* __restrict__ bias,
    const float* __restrict__ gamma, const float* __restrict__ beta,
    const float* __restrict__ mean,  const float* __restrict__ var,
    ushort* __restrict__ C,          // M x 128 bf16
    int M, int do_bn)
{
  constexpr int NK = K / 32;
  int tid  = threadIdx.x;
  int wid  = tid >> 6;
  int lane = tid & 63;
  int lr = lane & 15;
  int lg = lane >> 4;
  int nh = wid & 1;                      // N-half
  int m0 = blockIdx.x * 32 + (wid >> 1) * 16;

  int arow = m0 + lr;
  if (arow >= M) arow = M - 1;
  const ushort* Ap = A + (size_t)arow * K + lg * 8;

  bf16x8 afr[NK];
#pragma unroll
  for (int kk = 0; kk < NK; ++kk) afr[kk] = *(const bf16x8*)(Ap + kk * 32);

  f32x4 acc[4];
#pragma unroll
  for (int t = 0; t < 4; ++t) acc[t] = (f32x4){0.f, 0.f, 0.f, 0.f};

#pragma unroll
  for (int t = 0; t < 4; ++t) {
    const ushort* Bp = WT + (size_t)(nh * 64 + t * 16 + lr) * K + lg * 8;
#pragma unroll
    for (int kk = 0; kk < NK; ++kk) {
      bf16x8 bf = *(const bf16x8*)(Bp + kk * 32);
      acc[t] = __builtin_amdgcn_mfma_f32_16x16x32_bf16(afr[kk], bf, acc[t], 0, 0, 0);
    }
  }

#pragma unroll
  for (int t = 0; t < 4; ++t) {
    int c = nh * 64 + t * 16 + lr;
    float bs = 0.f, sc = 1.f, sh = 0.f;
    if (bias) bs = bias[c];
    if (do_bn) {
      float s = gamma[c] * rsqrtf(var[c] + BN_EPS);
      sc = s;
      sh = beta[c] - mean[c] * s;
    }
#pragma unroll
    for (int r = 0; r < 4; ++r) {
      int row = m0 + lg * 4 + r;
      if (row < M) {
        float v = acc[t][r];
        if (bias) {
          v += bs;
          v = fmaxf(v, 0.f);
          if (do_bn) { v = fmaf(v, sc, sh); v = fmaxf(v, 0.f); }
        }
        C[(size_t)row * HID + c] = f2b(v);
      }
    }
  }
}

// ================= layer-1 GEMM: fp32 A fused-convert, K=256 =================
__global__ __launch_bounds__(256) void mm_bf16_f32(
    const float* __restrict__ A,     // M x 256 fp32
    const ushort* __restrict__ WT,   // 128 x 256 bf16
    ushort* __restrict__ C,          // M x 128 bf16
    int M)
{
  constexpr int K = IN_DIM;
  constexpr int NK = K / 32;
  int tid  = threadIdx.x;
  int wid  = tid >> 6;
  int lane = tid & 63;
  int lr = lane & 15;
  int lg = lane >> 4;
  int nh = wid & 1;
  int m0 = blockIdx.x * 32 + (wid >> 1) * 16;

  int arow = m0 + lr;
  if (arow >= M) arow = M - 1;
  const float* Ap = A + (size_t)arow * K + lg * 8;

  bf16x8 afr[NK];
#pragma unroll
  for (int kk = 0; kk < NK; ++kk) {
    float4 a0 = *(const float4*)(Ap + kk * 32);
    float4 a1 = *(const float4*)(Ap + kk * 32 + 4);
    bf16x8 af;
    af[0] = (short)f2b(a0.x); af[1] = (short)f2b(a0.y);
    af[2] = (short)f2b(a0.z); af[3] = (short)f2b(a0.w);
    af[4] = (short)f2b(a1.x); af[5] = (short)f2b(a1.y);
    af[6] = (short)f2b(a1.z); af[7] = (short)f2b(a1.w);
    afr[kk] = af;
  }

  f32x4 acc[4];
#pragma unroll
  for (int t = 0; t < 4; ++t) acc[t] = (f32x4){0.f, 0.f, 0.f, 0.f};

#pragma unroll
  for (int t = 0; t < 4; ++t) {
    const ushort* Bp = WT + (size_t)(nh * 64 + t * 16 + lr) * K + lg * 8;
#pragma unroll
    for (int kk = 0; kk < NK; ++kk) {
      bf16x8 bf = *(const bf16x8*)(Bp + kk * 32);
      acc[t] = __builtin_amdgcn_mfma_f32_16x16x32_bf16(afr[kk], bf, acc[t], 0, 0, 0);
    }
  }

#pragma unroll
  for (int t = 0; t < 4; ++t) {
    int c = nh * 64 + t * 16 + lr;
#pragma unroll
    for (int r = 0; r < 4; ++r) {
      int row = m0 + lg * 4 + r;
      if (row < M) C[(size_t)row * HID + c] = f2b(acc[t][r]);
    }
  }
}

// ===== dual GEMM for pair head: C0 = A@W_top, C1 = A@W_bot (one A pass) =====
// WT is int_w1^T [128][256]; wave = 16 rows x 64 cols of BOTH C0 and C1
__global__ __launch_bounds__(256) void mm_bf16_dual(
    const ushort* __restrict__ A,    // M x 128 bf16
    const ushort* __restrict__ WT,   // 128 x 256 bf16
    ushort* __restrict__ C0,
    ushort* __restrict__ C1,
    int M)
{
  constexpr int NK = HID / 32;
  int tid  = threadIdx.x;
  int wid  = tid >> 6;
  int lane = tid & 63;
  int lr = lane & 15;
  int lg = lane >> 4;
  int nh = wid & 1;
  int m0 = blockIdx.x * 32 + (wid >> 1) * 16;

  int arow = m0 + lr;
  if (arow >= M) arow = M - 1;
  const ushort* Ap = A + (size_t)arow * HID + lg * 8;

  bf16x8 afr[NK];
#pragma unroll
  for (int kk = 0; kk < NK; ++kk) afr[kk] = *(const bf16x8*)(Ap + kk * 32);

  f32x4 acc[8];
#pragma unroll
  for (int t = 0; t < 8; ++t) acc[t] = (f32x4){0.f, 0.f, 0.f, 0.f};

#pragma unroll
  for (int t = 0; t < 8; ++t) {
    int half = t >> 2;                  // 0: W_top (k<128), 1: W_bot
    int nrow = nh * 64 + (t & 3) * 16 + lr;
    const ushort* Bp = WT + (size_t)nrow * 256 + half * 128 + lg * 8;
#pragma unroll
    for (int kk = 0; kk < NK; ++kk) {
      bf16x8 bf = *(const bf16x8*)(Bp + kk * 32);
      acc[t] = __builtin_amdgcn_mfma_f32_16x16x32_bf16(afr[kk], bf, acc[t], 0, 0, 0);
    }
  }

#pragma unroll
  for (int t = 0; t < 8; ++t) {
    int c = nh * 64 + (t & 3) * 16 + lr;
    ushort* C = (t < 4) ? C0 : C1;
#pragma unroll
    for (int r = 0; r < 4; ++r) {
      int row = m0 + lg * 4 + r;
      if (row < M) C[(size_t)row * HID + c] = f2b(acc[t][r]);
    }
  }
}

// ===== fused aggregate (bf16), 8-way unrolled =====
// x[n] = relu((1+eps)*t[n] + sum t[s] + b)
__global__ __launch_bounds__(256) void gather_kernel(
    const ushort* __restrict__ t,
    const int* __restrict__ row_ptr,
    const int* __restrict__ esrc,
    const float* __restrict__ epsP, int layer,
    const float* __restrict__ bias,
    ushort* __restrict__ x)
{
  int wave = (blockIdx.x * blockDim.x + threadIdx.x) >> 6;
  int lane = threadIdx.x & 63;
  if (wave >= N_NODES) return;
  int beg = row_ptr[wave];
  int end = row_ptr[wave + 1];
  float scale = 1.0f + epsP[layer];

  unsigned int u = *(const unsigned int*)(t + (size_t)wave * HID + lane * 2);
  float ax = b2f((ushort)(u & 0xffff)) * scale;
  float ay = b2f((ushort)(u >> 16)) * scale;

  int i = beg;
  for (; i + 8 <= end; i += 8) {
    int s[8];
#pragma unroll
    for (int j = 0; j < 8; ++j) s[j] = esrc[i + j];
    unsigned int v[8];
#pragma unroll
    for (int j = 0; j < 8; ++j)
      v[j] = *(const unsigned int*)(t + (size_t)s[j] * HID + lane * 2);
#pragma unroll
    for (int j = 0; j < 8; ++j) {
      ax += b2f((ushort)(v[j] & 0xffff));
      ay += b2f((ushort)(v[j] >> 16));
    }
  }
  for (; i < end; ++i) {
    int s = esrc[i];
    unsigned int v = *(const unsigned int*)(t + (size_t)s * HID + lane * 2);
    ax += b2f((ushort)(v & 0xffff));
    ay += b2f((ushort)(v >> 16));
  }

  float2 b = *(const float2*)(bias + lane * 2);
  ax = fmaxf(ax + b.x, 0.0f);
  ay = fmaxf(ay + b.y, 0.0f);
  unsigned int o = ((unsigned int)f2b(ay) << 16) | f2b(ax);
  *(unsigned int*)(x + (size_t)wave * HID + lane * 2) = o;
}

// ===== fused MFMA pair head: out = relu(P1[n0]+P2[n1]+b1) @ w2 + b2 =====
__global__ __launch_bounds__(256) void pair_mfma(
    const ushort* __restrict__ P1,   // N_NODES x 128 bf16
    const ushort* __restrict__ P2,
    const int* __restrict__ ppi,
    const int* __restrict__ idx,
    const float* __restrict__ b1,    // 128 fp32
    const ushort* __restrict__ w2t,  // 16 x 128 bf16 (padded transpose of int_w2)
    const float* __restrict__ b2,    // 7
    float* __restrict__ out)         // BATCH x 7 fp32
{
  int tid  = threadIdx.x;
  int wid  = tid >> 6;
  int lane = tid & 63;
  int lr = lane & 15;
  int lg = lane >> 4;
  int p0 = blockIdx.x * 64 + wid * 16;
  int p  = p0 + lr;

  int pi = idx[p];
  int n0 = ppi[2 * pi];
  int n1 = ppi[2 * pi + 1];

  const ushort* r1 = P1 + (size_t)n0 * HID + lg * 8;
  const ushort* r2 = P2 + (size_t)n1 * HID + lg * 8;
  const float*  bp = b1 + lg * 8;
  const ushort* wp = w2t + (size_t)lr * HID + lg * 8;

  f32x4 acc = (f32x4){0.f, 0.f, 0.f, 0.f};
#pragma unroll
  for (int kk = 0; kk < HID; kk += 32) {
    bf16x8 a1v = *(const bf16x8*)(r1 + kk);
    bf16x8 a2v = *(const bf16x8*)(r2 + kk);
    float4 bb0 = *(const float4*)(bp + kk);
    float4 bb1 = *(const float4*)(bp + kk + 4);
    float bbf[8] = {bb0.x, bb0.y, bb0.z, bb0.w, bb1.x, bb1.y, bb1.z, bb1.w};
    bf16x8 af;
#pragma unroll
    for (int j = 0; j < 8; ++j) {
      float v = b2f((ushort)a1v[j]) + b2f((ushort)a2v[j]) + bbf[j];
      af[j] = (short)f2b(fmaxf(v, 0.f));
    }
    bf16x8 bf = *(const bf16x8*)(wp + kk);
    acc = __builtin_amdgcn_mfma_f32_16x16x32_bf16(af, bf, acc, 0, 0, 0);
  }

  if (lr < OUT_DIM) {
    float bias2 = b2[lr];
#pragma unroll
    for (int r = 0; r < 4; ++r) {
      out[(size_t)(p0 + lg * 4 + r) * OUT_DIM + lr] = acc[r] + bias2;
    }
  }
}

extern "C" void kernel_launch(void* const* d_in, const int* in_sizes, int n_in,
                              void* d_out, int out_size, void* d_ws, size_t ws_size,
                              hipStream_t stream) {
  const float* feat   = (const float*)d_in[0];
  const int*   src    = (const int*)d_in[1];
  const int*   dst    = (const int*)d_in[2];
  const int*   ppi    = (const int*)d_in[3];
  const int*   idx    = (const int*)d_in[4];
  const float* eps    = (const float*)d_in[5];
  const float* w1_in  = (const float*)d_in[6];
  const float* b1_in  = (const float*)d_in[7];
  const float* w2_in  = (const float*)d_in[8];
  const float* b2_in  = (const float*)d_in[9];
  const float* hw1    = (const float*)d_in[10];
  const float* hb1    = (const float*)d_in[11];
  const float* hw2    = (const float*)d_in[12];
  const float* hb2    = (const float*)d_in[13];
  const float* bng    = (const float*)d_in[14];
  const float* bnb    = (const float*)d_in[15];
  const float* bnm    = (const float*)d_in[16];
  const float* bnv    = (const float*)d_in[17];
  const float* lin_w  = (const float*)d_in[18];
  const float* lin_b  = (const float*)d_in[19];
  const float* int_w1 = (const float*)d_in[20];
  const float* int_b1 = (const float*)d_in[21];
  const float* int_w2 = (const float*)d_in[22];
  const float* int_b2 = (const float*)d_in[23];
  float* out = (float*)d_out;

  // ---- workspace layout ----
  const size_t NB = (size_t)N_NODES * HID;   // ushort count per node buf
  ushort* b0 = (ushort*)d_ws;      // t / P1
  ushort* b1 = b0 + NB;            // x / P2
  ushort* b2 = b1 + NB;            // h
  ushort* b3 = b2 + NB;            // hL
  ushort* WT1  = b3 + NB;          // 128x256
  ushort* WT2  = WT1 + 32768;      // 128x128
  ushort* WH1a = WT2 + 16384;
  ushort* WH1b = WH1a + 16384;
  ushort* WH2a = WH1b + 16384;
  ushort* WH2b = WH2a + 16384;
  ushort* WTL  = WH2b + 16384;
  ushort* WTI  = WTL + 16384;      // 128x256 (int_w1^T)
  ushort* W2T  = WTI + 32768;      // 16x128 (int_w2^T padded)
  int* row_ptr = (int*)(W2T + 2048);
  int* cursor  = row_ptr + N_NODES + 8;    // deg, then cursor (aliased)
  int* esrc    = cursor + N_NODES;
  int* part    = esrc + N_EDGES;           // 256 ints

  int mmBlocks = (N_NODES + 31) / 32;      // 32 rows/block
  int edgeBlocks = (N_EDGES + 255) / 256;
  int nodeWaveBlocks = (N_NODES + 3) / 4;
  int pairBlocks = BATCH / 64;             // 4 waves x 16 pairs

  // ---- CSR build + weight conversion ----
  hipMemsetAsync(cursor, 0, N_NODES * sizeof(int), stream);
  hist_kernel<<<edgeBlocks, 256, 0, stream>>>(dst, cursor);
  scan_partial<<<SCAN_BLK, 256, 0, stream>>>(cursor, part);
  scan_offsets<<<1, 256, 0, stream>>>(part);
  scan_final<<<SCAN_BLK, 256, 0, stream>>>(cursor, part, row_ptr, cursor);
  scatter_kernel<<<edgeBlocks, 256, 0, stream>>>(src, dst, cursor, esrc);
  convw_kernel<<<640, 256, 0, stream>>>(w1_in, w2_in, hw1, hw1 + 128 * 128,
                                        hw2, hw2 + 128 * 128, lin_w, int_w1,
                                        WT1, WT2, WH1a, WH1b, WH2a, WH2b, WTL, WTI);
  convw2_kernel<<<8, 256, 0, stream>>>(int_w2, W2T);

  // ---- layer 1: t = feat@w1 (K=256, fp32 A fused-convert), gather, mm2+BN ----
  mm_bf16_f32<<<mmBlocks, 256, 0, stream>>>(feat, WT1, b0, N_NODES);
  gather_kernel<<<nodeWaveBlocks, 256, 0, stream>>>(b0, row_ptr, esrc, eps, 0, b1_in, b1);
  mm_bf16_t<HID><<<mmBlocks, 256, 0, stream>>>(b1, WT2, b2_in,
                                               bng, bnb, bnm, bnv,
                                               b2, N_NODES, 1);

  // ---- layers 2..3 ----
  ushort* WH1[2] = {WH1a, WH1b};
  ushort* WH2[2] = {WH2a, WH2b};
  for (int l = 1; l < 3; ++l) {
    mm_bf16_t<HID><<<mmBlocks, 256, 0, stream>>>(b2, WH1[l - 1], nullptr,
                                                 nullptr, nullptr, nullptr, nullptr,
                                                 b0, N_NODES, 0);
    gather_kernel<<<nodeWaveBlocks, 256, 0, stream>>>(b0, row_ptr, esrc, eps, l,
                                                      hb1 + (size_t)(l - 1) * HID, b1);
    mm_bf16_t<HID><<<mmBlocks, 256, 0, stream>>>(b1, WH2[l - 1],
                                                 hb2 + (size_t)(l - 1) * HID,
                                                 bng + l * HID, bnb + l * HID,
                                                 bnm + l * HID, bnv + l * HID,
                                                 b2, N_NODES, 1);
  }

  // ---- lin: hL = relu(h@lin_w + lin_b) ----
  mm_bf16_t<HID><<<mmBlocks, 256, 0, stream>>>(b2, WTL, lin_b,
                                               nullptr, nullptr, nullptr, nullptr,
                                               b3, N_NODES, 0);

  // ---- pair head: P1,P2 in one pass, then fused MFMA head ----
  mm_bf16_dual<<<mmBlocks, 256, 0, stream>>>(b3, WTI, b0, b1, N_NODES);
  pair_mfma<<<pairBlocks, 256, 0, stream>>>(b0, b1, ppi, idx,
                                            int_b1, W2T, int_b2, out);
}

// Round 17
// 458.588 us; speedup vs baseline: 9.4861x; 1.0776x over previous
//
#include <hip/hip_runtime.h>

#define N_NODES 50000
#define N_EDGES 500000
#define IN_DIM  256
#define HID     128
#define OUT_DIM 7
#define NPAIRS  100000
#define BATCH   65536
#define BN_EPS  1e-5f

#define SCAN_BLK 196   // ceil(50000/256)
#define LDSP 136       // padded LDS row stride (shorts): 272B = 17*16B, aligned + ~conflict-free

typedef __attribute__((ext_vector_type(8))) short bf16x8;   // 8 bf16 = 4 VGPRs
typedef __attribute__((ext_vector_type(4))) float f32x4;

__device__ inline float b2f(ushort u) {
  unsigned int x = ((unsigned int)u) << 16;
  return __uint_as_float(x);
}
__device__ inline ushort f2b(float f) {  // round-to-nearest-even
  unsigned int x = __float_as_uint(f);
  unsigned int r = (x + 0x7fffu + ((x >> 16) & 1u)) >> 16;
  return (ushort)r;
}

// ================= CSR build (once per call) =================
__global__ void hist_kernel(const int* __restrict__ dst, int* __restrict__ deg) {
  int e = blockIdx.x * blockDim.x + threadIdx.x;
  if (e < N_EDGES) atomicAdd(&deg[dst[e]], 1);
}

__global__ __launch_bounds__(256) void scan_partial(const int* __restrict__ deg,
                                                    int* __restrict__ part) {
  __shared__ int s[256];
  int t = threadIdx.x;
  int i = blockIdx.x * 256 + t;
  s[t] = (i < N_NODES) ? deg[i] : 0;
  __syncthreads();
  for (int off = 128; off > 0; off >>= 1) {
    if (t < off) s[t] += s[t + off];
    __syncthreads();
  }
  if (t == 0) part[blockIdx.x] = s[0];
}

__global__ __launch_bounds__(256) void scan_offsets(int* __restrict__ part) {
  __shared__ int s[256];
  int t = threadIdx.x;
  int v = (t < SCAN_BLK) ? part[t] : 0;
  s[t] = v;
  __syncthreads();
  for (int off = 1; off < 256; off <<= 1) {
    int u = (t >= off) ? s[t - off] : 0;
    __syncthreads();
    s[t] += u;
    __syncthreads();
  }
  if (t < SCAN_BLK) part[t] = s[t] - v;   // exclusive
}

__global__ __launch_bounds__(256) void scan_final(const int* __restrict__ deg,
                                                  const int* __restrict__ part,
                                                  int* __restrict__ row_ptr,
                                                  int* __restrict__ cursor) {
  __shared__ int s[256];
  int t = threadIdx.x;
  int i = blockIdx.x * 256 + t;
  int v = (i < N_NODES) ? deg[i] : 0;
  s[t] = v;
  __syncthreads();
  for (int off = 1; off < 256; off <<= 1) {
    int u = (t >= off) ? s[t - off] : 0;
    __syncthreads();
    s[t] += u;
    __syncthreads();
  }
  int excl = s[t] - v + part[blockIdx.x];
  if (i < N_NODES) {
    row_ptr[i] = excl;
    cursor[i] = excl;
    if (i == N_NODES - 1) row_ptr[N_NODES] = excl + v;  // = N_EDGES
  }
}

__global__ void scatter_kernel(const int* __restrict__ src,
                               const int* __restrict__ dst,
                               int* __restrict__ cursor,
                               int* __restrict__ esrc) {
  int e = blockIdx.x * blockDim.x + threadIdx.x;
  if (e < N_EDGES) {
    int pos = atomicAdd(&cursor[dst[e]], 1);
    esrc[pos] = src[e];
  }
}

// ================= weight convert+transpose: WT[n][k] = bf16(W[k][n]) =================
__global__ void convw_kernel(const float* s0, const float* s1, const float* s2,
                             const float* s3, const float* s4, const float* s5,
                             const float* s6, const float* s7,
                             ushort* d0, ushort* d1, ushort* d2, ushort* d3,
                             ushort* d4, ushort* d5, ushort* d6, ushort* d7) {
  int gid = blockIdx.x * blockDim.x + threadIdx.x;
  const float* srcs[8] = {s0, s1, s2, s3, s4, s5, s6, s7};
  ushort* dsts[8] = {d0, d1, d2, d3, d4, d5, d6, d7};
  const int Ks[8] = {256, 128, 128, 128, 128, 128, 128, 256};
  const int off[9] = {0, 32768, 49152, 65536, 81920, 98304, 114688, 131072, 163840};
  if (gid >= 163840) return;
  int slot = 0;
#pragma unroll
  for (int s = 1; s < 8; ++s) if (gid >= off[s]) slot = s;
  int i = gid - off[slot];
  int K = Ks[slot];
  int k = i >> 7;          // N = 128 always
  int n = i & 127;
  dsts[slot][(size_t)n * K + k] = f2b(srcs[slot][(size_t)k * 128 + n]);
}

// ---- int_w2 (128x7 fp32) -> w2t (16x128 bf16, rows >=7 zero) ----
__global__ void convw2_kernel(const float* __restrict__ w2, ushort* __restrict__ w2t) {
  int gid = blockIdx.x * blockDim.x + threadIdx.x;
  if (gid >= 16 * 128) return;
  int c = gid >> 7;
  int k = gid & 127;
  w2t[gid] = (c < OUT_DIM) ? f2b(w2[(size_t)k * OUT_DIM + c]) : (ushort)0;
}

// ================= layer-1 GEMM: fp32 A fused-convert, K=256, grid-strided =================
__global__ __launch_bounds__(256) void mm_bf16_f32(
    const float* __restrict__ A,     // M x 256 fp32
    const ushort* __restrict__ WT,   // 128 x 256 bf16
    ushort* __restrict__ C,          // M x 128 bf16
    int M, int nChunks)
{
  constexpr int K = IN_DIM;
  constexpr int NK = K / 32;
  int tid  = threadIdx.x;
  int wid  = tid >> 6;
  int lane = tid & 63;
  int lr = lane & 15;
  int lg = lane >> 4;
  int nh = wid & 1;

  for (int ch = blockIdx.x; ch < nChunks; ch += gridDim.x) {
    int m0 = ch * 32 + (wid >> 1) * 16;
    int arow = m0 + lr;
    if (arow >= M) arow = M - 1;
    const float* Ap = A + (size_t)arow * K + lg * 8;

    bf16x8 afr[NK];
#pragma unroll
    for (int kk = 0; kk < NK; ++kk) {
      float4 a0 = *(const float4*)(Ap + kk * 32);
      float4 a1 = *(const float4*)(Ap + kk * 32 + 4);
      bf16x8 af;
      af[0] = (short)f2b(a0.x); af[1] = (short)f2b(a0.y);
      af[2] = (short)f2b(a0.z); af[3] = (short)f2b(a0.w);
      af[4] = (short)f2b(a1.x); af[5] = (short)f2b(a1.y);
      af[6] = (short)f2b(a1.z); af[7] = (short)f2b(a1.w);
      afr[kk] = af;
    }

    f32x4 acc[4];
#pragma unroll
    for (int t = 0; t < 4; ++t) acc[t] = (f32x4){0.f, 0.f, 0.f, 0.f};

#pragma unroll
    for (int t = 0; t < 4; ++t) {
      const ushort* Bp = WT + (size_t)(nh * 64 + t * 16 + lr) * K + lg * 8;
#pragma unroll
      for (int kk = 0; kk < NK; ++kk) {
        bf16x8 bf = *(const bf16x8*)(Bp + kk * 32);
        acc[t] = __builtin_amdgcn_mfma_f32_16x16x32_bf16(afr[kk], bf, acc[t], 0, 0, 0);
      }
    }

#pragma unroll
    for (int t = 0; t < 4; ++t) {
      int c = nh * 64 + t * 16 + lr;
#pragma unroll
      for (int r = 0; r < 4; ++r) {
        int row = m0 + lg * 4 + r;
        if (row < M) C[(size_t)row * HID + c] = f2b(acc[t][r]);
      }
    }
  }
}

// ===== fused mid-layer: t' = (BN o relu(x@W2+b2)) @ W1n =====
// block = 32 rows; h tile lives in LDS only
__global__ __launch_bounds__(256) void fused_mid(
    const ushort* __restrict__ x,    // M x 128 bf16
    const ushort* __restrict__ WT2,  // 128 x 128 bf16 (w2^T)
    const float* __restrict__ bias2,
    const float* __restrict__ gamma, const float* __restrict__ beta,
    const float* __restrict__ mean,  const float* __restrict__ var,
    const ushort* __restrict__ WT1n, // 128 x 128 bf16 (next w1^T)
    ushort* __restrict__ tOut,       // M x 128 bf16
    int M)
{
  __shared__ ushort hs[32][LDSP];
  constexpr int NK = HID / 32;
  int tid  = threadIdx.x;
  int wid  = tid >> 6;
  int lane = tid & 63;
  int lr = lane & 15;
  int lg = lane >> 4;
  int nh = wid & 1;
  int wr = (wid >> 1) * 16;
  int m0 = blockIdx.x * 32 + wr;

  // ---- stage 1: h = BN(relu(x@W2+b2)) -> LDS ----
  {
    int arow = m0 + lr;
    if (arow >= M) arow = M - 1;
    const ushort* Ap = x + (size_t)arow * HID + lg * 8;
    bf16x8 afr[NK];
#pragma unroll
    for (int kk = 0; kk < NK; ++kk) afr[kk] = *(const bf16x8*)(Ap + kk * 32);

    f32x4 acc[4];
#pragma unroll
    for (int t = 0; t < 4; ++t) acc[t] = (f32x4){0.f, 0.f, 0.f, 0.f};
#pragma unroll
    for (int t = 0; t < 4; ++t) {
      const ushort* Bp = WT2 + (size_t)(nh * 64 + t * 16 + lr) * HID + lg * 8;
#pragma unroll
      for (int kk = 0; kk < NK; ++kk) {
        bf16x8 bf = *(const bf16x8*)(Bp + kk * 32);
        acc[t] = __builtin_amdgcn_mfma_f32_16x16x32_bf16(afr[kk], bf, acc[t], 0, 0, 0);
      }
    }
#pragma unroll
    for (int t = 0; t < 4; ++t) {
      int c = nh * 64 + t * 16 + lr;
      float bs = bias2[c];
      float s = gamma[c] * rsqrtf(var[c] + BN_EPS);
      float sh = beta[c] - mean[c] * s;
#pragma unroll
      for (int r = 0; r < 4; ++r) {
        float v = acc[t][r] + bs;
        v = fmaxf(v, 0.f);
        v = fmaf(v, s, sh);
        v = fmaxf(v, 0.f);
        hs[wr + lg * 4 + r][c] = f2b(v);
      }
    }
  }
  __syncthreads();

  // ---- stage 2: t' = h @ W1n -> global ----
  {
    int rl = wr + lr;
    bf16x8 afr[NK];
#pragma unroll
    for (int kk = 0; kk < NK; ++kk)
      afr[kk] = *(const bf16x8*)&hs[rl][kk * 32 + lg * 8];

    f32x4 acc[4];
#pragma unroll
    for (int t = 0; t < 4; ++t) acc[t] = (f32x4){0.f, 0.f, 0.f, 0.f};
#pragma unroll
    for (int t = 0; t < 4; ++t) {
      const ushort* Bp = WT1n + (size_t)(nh * 64 + t * 16 + lr) * HID + lg * 8;
#pragma unroll
      for (int kk = 0; kk < NK; ++kk) {
        bf16x8 bf = *(const bf16x8*)(Bp + kk * 32);
        acc[t] = __builtin_amdgcn_mfma_f32_16x16x32_bf16(afr[kk], bf, acc[t], 0, 0, 0);
      }
    }
#pragma unroll
    for (int t = 0; t < 4; ++t) {
      int c = nh * 64 + t * 16 + lr;
#pragma unroll
      for (int r = 0; r < 4; ++r) {
        int row = m0 + lg * 4 + r;
        if (row < M) tOut[(size_t)row * HID + c] = f2b(acc[t][r]);
      }
    }
  }
}

// ===== fused tail: x -> h(BN) -> hL(lin) -> P1,P2(dual) =====
__global__ __launch_bounds__(256) void fused_tail(
    const ushort* __restrict__ x,    // M x 128 bf16
    const ushort* __restrict__ WT2,  // 128x128 (hw2_1^T)
    const float* __restrict__ bias2,
    const float* __restrict__ gamma, const float* __restrict__ beta,
    const float* __restrict__ mean,  const float* __restrict__ var,
    const ushort* __restrict__ WTL,  // 128x128 (lin^T)
    const float* __restrict__ linb,
    const ushort* __restrict__ WTI,  // 128x256 (int_w1^T)
    ushort* __restrict__ P1, ushort* __restrict__ P2,
    int M)
{
  __shared__ ushort hs[32][LDSP];
  __shared__ ushort ls[32][LDSP];
  constexpr int NK = HID / 32;
  int tid  = threadIdx.x;
  int wid  = tid >> 6;
  int lane = tid & 63;
  int lr = lane & 15;
  int lg = lane >> 4;
  int nh = wid & 1;
  int wr = (wid >> 1) * 16;
  int m0 = blockIdx.x * 32 + wr;

  // ---- stage 1: h = BN(relu(x@W2+b2)) -> hs ----
  {
    int arow = m0 + lr;
    if (arow >= M) arow = M - 1;
    const ushort* Ap = x + (size_t)arow * HID + lg * 8;
    bf16x8 afr[NK];
#pragma unroll
    for (int kk = 0; kk < NK; ++kk) afr[kk] = *(const bf16x8*)(Ap + kk * 32);
    f32x4 acc[4];
#pragma unroll
    for (int t = 0; t < 4; ++t) acc[t] = (f32x4){0.f, 0.f, 0.f, 0.f};
#pragma unroll
    for (int t = 0; t < 4; ++t) {
      const ushort* Bp = WT2 + (size_t)(nh * 64 + t * 16 + lr) * HID + lg * 8;
#pragma unroll
      for (int kk = 0; kk < NK; ++kk) {
        bf16x8 bf = *(const bf16x8*)(Bp + kk * 32);
        acc[t] = __builtin_amdgcn_mfma_f32_16x16x32_bf16(afr[kk], bf, acc[t], 0, 0, 0);
      }
    }
#pragma unroll
    for (int t = 0; t < 4; ++t) {
      int c = nh * 64 + t * 16 + lr;
      float bs = bias2[c];
      float s = gamma[c] * rsqrtf(var[c] + BN_EPS);
      float sh = beta[c] - mean[c] * s;
#pragma unroll
      for (int r = 0; r < 4; ++r) {
        float v = acc[t][r] + bs;
        v = fmaxf(v, 0.f);
        v = fmaf(v, s, sh);
        v = fmaxf(v, 0.f);
        hs[wr + lg * 4 + r][c] = f2b(v);
      }
    }
  }
  __syncthreads();

  // ---- stage 2: hL = relu(h@lin + linb) -> ls ----
  {
    int rl = wr + lr;
    bf16x8 afr[NK];
#pragma unroll
    for (int kk = 0; kk < NK; ++kk)
      afr[kk] = *(const bf16x8*)&hs[rl][kk * 32 + lg * 8];
    f32x4 acc[4];
#pragma unroll
    for (int t = 0; t < 4; ++t) acc[t] = (f32x4){0.f, 0.f, 0.f, 0.f};
#pragma unroll
    for (int t = 0; t < 4; ++t) {
      const ushort* Bp = WTL + (size_t)(nh * 64 + t * 16 + lr) * HID + lg * 8;
#pragma unroll
      for (int kk = 0; kk < NK; ++kk) {
        bf16x8 bf = *(const bf16x8*)(Bp + kk * 32);
        acc[t] = __builtin_amdgcn_mfma_f32_16x16x32_bf16(afr[kk], bf, acc[t], 0, 0, 0);
      }
    }
#pragma unroll
    for (int t = 0; t < 4; ++t) {
      int c = nh * 64 + t * 16 + lr;
      float bs = linb[c];
#pragma unroll
      for (int r = 0; r < 4; ++r) {
        float v = fmaxf(acc[t][r] + bs, 0.f);
        ls[wr + lg * 4 + r][c] = f2b(v);
      }
    }
  }
  __syncthreads();

  // ---- stage 3: P1 = hL@W_top, P2 = hL@W_bot -> global ----
  {
    int rl = wr + lr;
    bf16x8 afr[NK];
#pragma unroll
    for (int kk = 0; kk < NK; ++kk)
      afr[kk] = *(const bf16x8*)&ls[rl][kk * 32 + lg * 8];
    f32x4 acc[8];
#pragma unroll
    for (int t = 0; t < 8; ++t) acc[t] = (f32x4){0.f, 0.f, 0.f, 0.f};
#pragma unroll
    for (int t = 0; t < 8; ++t) {
      int half = t >> 2;
      int nrow = nh * 64 + (t & 3) * 16 + lr;
      const ushort* Bp = WTI + (size_t)nrow * 256 + half * 128 + lg * 8;
#pragma unroll
      for (int kk = 0; kk < NK; ++kk) {
        bf16x8 bf = *(const bf16x8*)(Bp + kk * 32);
        acc[t] = __builtin_amdgcn_mfma_f32_16x16x32_bf16(afr[kk], bf, acc[t], 0, 0, 0);
      }
    }
#pragma unroll
    for (int t = 0; t < 8; ++t) {
      int c = nh * 64 + (t & 3) * 16 + lr;
      ushort* P = (t < 4) ? P1 : P2;
#pragma unroll
      for (int r = 0; r < 4; ++r) {
        int row = m0 + lg * 4 + r;
        if (row < M) P[(size_t)row * HID + c] = f2b(acc[t][r]);
      }
    }
  }
}

// ===== fused aggregate (bf16), 8-way unrolled =====
__global__ __launch_bounds__(256) void gather_kernel(
    const ushort* __restrict__ t,
    const int* __restrict__ row_ptr,
    const int* __restrict__ esrc,
    const float* __restrict__ epsP, int layer,
    const float* __restrict__ bias,
    ushort* __restrict__ x)
{
  int wave = (blockIdx.x * blockDim.x + threadIdx.x) >> 6;
  int lane = threadIdx.x & 63;
  if (wave >= N_NODES) return;
  int beg = row_ptr[wave];
  int end = row_ptr[wave + 1];
  float scale = 1.0f + epsP[layer];

  unsigned int u = *(const unsigned int*)(t + (size_t)wave * HID + lane * 2);
  float ax = b2f((ushort)(u & 0xffff)) * scale;
  float ay = b2f((ushort)(u >> 16)) * scale;

  int i = beg;
  for (; i + 8 <= end; i += 8) {
    int s[8];
#pragma unroll
    for (int j = 0; j < 8; ++j) s[j] = esrc[i + j];
    unsigned int v[8];
#pragma unroll
    for (int j = 0; j < 8; ++j)
      v[j] = *(const unsigned int*)(t + (size_t)s[j] * HID + lane * 2);
#pragma unroll
    for (int j = 0; j < 8; ++j) {
      ax += b2f((ushort)(v[j] & 0xffff));
      ay += b2f((ushort)(v[j] >> 16));
    }
  }
  for (; i < end; ++i) {
    int s = esrc[i];
    unsigned int v = *(const unsigned int*)(t + (size_t)s * HID + lane * 2);
    ax += b2f((ushort)(v & 0xffff));
    ay += b2f((ushort)(v >> 16));
  }

  float2 b = *(const float2*)(bias + lane * 2);
  ax = fmaxf(ax + b.x, 0.0f);
  ay = fmaxf(ay + b.y, 0.0f);
  unsigned int o = ((unsigned int)f2b(ay) << 16) | f2b(ax);
  *(unsigned int*)(x + (size_t)wave * HID + lane * 2) = o;
}

// ===== fused MFMA pair head: out = relu(P1[n0]+P2[n1]+b1) @ w2 + b2 =====
__global__ __launch_bounds__(256) void pair_mfma(
    const ushort* __restrict__ P1,
    const ushort* __restrict__ P2,
    const int* __restrict__ ppi,
    const int* __restrict__ idx,
    const float* __restrict__ b1,
    const ushort* __restrict__ w2t,  // 16 x 128 bf16
    const float* __restrict__ b2,
    float* __restrict__ out)
{
  int tid  = threadIdx.x;
  int wid  = tid >> 6;
  int lane = tid & 63;
  int lr = lane & 15;
  int lg = lane >> 4;
  int p0 = blockIdx.x * 64 + wid * 16;
  int p  = p0 + lr;

  int pi = idx[p];
  int n0 = ppi[2 * pi];
  int n1 = ppi[2 * pi + 1];

  const ushort* r1 = P1 + (size_t)n0 * HID + lg * 8;
  const ushort* r2 = P2 + (size_t)n1 * HID + lg * 8;
  const float*  bp = b1 + lg * 8;
  const ushort* wp = w2t + (size_t)lr * HID + lg * 8;

  f32x4 acc = (f32x4){0.f, 0.f, 0.f, 0.f};
#pragma unroll
  for (int kk = 0; kk < HID; kk += 32) {
    bf16x8 a1v = *(const bf16x8*)(r1 + kk);
    bf16x8 a2v = *(const bf16x8*)(r2 + kk);
    float4 bb0 = *(const float4*)(bp + kk);
    float4 bb1 = *(const float4*)(bp + kk + 4);
    float bbf[8] = {bb0.x, bb0.y, bb0.z, bb0.w, bb1.x, bb1.y, bb1.z, bb1.w};
    bf16x8 af;
#pragma unroll
    for (int j = 0; j < 8; ++j) {
      float v = b2f((ushort)a1v[j]) + b2f((ushort)a2v[j]) + bbf[j];
      af[j] = (short)f2b(fmaxf(v, 0.f));
    }
    bf16x8 bf = *(const bf16x8*)(wp + kk);
    acc = __builtin_amdgcn_mfma_f32_16x16x32_bf16(af, bf, acc, 0, 0, 0);
  }

  if (lr < OUT_DIM) {
    float bias2 = b2[lr];
#pragma unroll
    for (int r = 0; r < 4; ++r) {
      out[(size_t)(p0 + lg * 4 + r) * OUT_DIM + lr] = acc[r] + bias2;
    }
  }
}

extern "C" void kernel_launch(void* const* d_in, const int* in_sizes, int n_in,
                              void* d_out, int out_size, void* d_ws, size_t ws_size,
                              hipStream_t stream) {
  const float* feat   = (const float*)d_in[0];
  const int*   src    = (const int*)d_in[1];
  const int*   dst    = (const int*)d_in[2];
  const int*   ppi    = (const int*)d_in[3];
  const int*   idx    = (const int*)d_in[4];
  const float* eps    = (const float*)d_in[5];
  const float* w1_in  = (const float*)d_in[6];
  const float* b1_in  = (const float*)d_in[7];
  const float* w2_in  = (const float*)d_in[8];
  const float* b2_in  = (const float*)d_in[9];
  const float* hw1    = (const float*)d_in[10];
  const float* hb1    = (const float*)d_in[11];
  const float* hw2    = (const float*)d_in[12];
  const float* hb2    = (const float*)d_in[13];
  const float* bng    = (const float*)d_in[14];
  const float* bnb    = (const float*)d_in[15];
  const float* bnm    = (const float*)d_in[16];
  const float* bnv    = (const float*)d_in[17];
  const float* lin_w  = (const float*)d_in[18];
  const float* lin_b  = (const float*)d_in[19];
  const float* int_w1 = (const float*)d_in[20];
  const float* int_b1 = (const float*)d_in[21];
  const float* int_w2 = (const float*)d_in[22];
  const float* int_b2 = (const float*)d_in[23];
  float* out = (float*)d_out;

  // ---- workspace layout ----
  const size_t NB = (size_t)N_NODES * HID;
  ushort* b0 = (ushort*)d_ws;      // t / P1
  ushort* b1 = b0 + NB;            // x / P2
  ushort* b2 = b1 + NB;            // P2 partner (t is reused: b0=t then P1)
  ushort* WT1  = b2 + NB;          // 128x256
  ushort* WT2  = WT1 + 32768;      // 128x128
  ushort* WH1a = WT2 + 16384;
  ushort* WH1b = WH1a + 16384;
  ushort* WH2a = WH1b + 16384;
  ushort* WH2b = WH2a + 16384;
  ushort* WTL  = WH2b + 16384;
  ushort* WTI  = WTL + 16384;      // 128x256 (int_w1^T)
  ushort* W2T  = WTI + 32768;      // 16x128 (int_w2^T padded)
  int* row_ptr = (int*)(W2T + 2048);
  int* cursor  = row_ptr + N_NODES + 8;
  int* esrc    = cursor + N_NODES;
  int* part    = esrc + N_EDGES;

  int mmBlocks = (N_NODES + 31) / 32;      // 1563
  int edgeBlocks = (N_EDGES + 255) / 256;
  int nodeWaveBlocks = (N_NODES + 3) / 4;
  int pairBlocks = BATCH / 64;

  // ---- CSR build + weight conversion ----
  hipMemsetAsync(cursor, 0, N_NODES * sizeof(int), stream);
  hist_kernel<<<edgeBlocks, 256, 0, stream>>>(dst, cursor);
  scan_partial<<<SCAN_BLK, 256, 0, stream>>>(cursor, part);
  scan_offsets<<<1, 256, 0, stream>>>(part);
  scan_final<<<SCAN_BLK, 256, 0, stream>>>(cursor, part, row_ptr, cursor);
  scatter_kernel<<<edgeBlocks, 256, 0, stream>>>(src, dst, cursor, esrc);
  convw_kernel<<<640, 256, 0, stream>>>(w1_in, w2_in, hw1, hw1 + 128 * 128,
                                        hw2, hw2 + 128 * 128, lin_w, int_w1,
                                        WT1, WT2, WH1a, WH1b, WH2a, WH2b, WTL, WTI);
  convw2_kernel<<<8, 256, 0, stream>>>(int_w2, W2T);

  // ---- layer 1: t1 = feat@w1 (grid-strided), gather -> x1 ----
  mm_bf16_f32<<<784, 256, 0, stream>>>(feat, WT1, b0, N_NODES, mmBlocks);
  gather_kernel<<<nodeWaveBlocks, 256, 0, stream>>>(b0, row_ptr, esrc, eps, 0, b1_in, b1);

  // ---- fused: x1 -> h1 -> t2 ----
  fused_mid<<<mmBlocks, 256, 0, stream>>>(b1, WT2, b2_in,
                                          bng, bnb, bnm, bnv,
                                          WH1a, b0, N_NODES);
  gather_kernel<<<nodeWaveBlocks, 256, 0, stream>>>(b0, row_ptr, esrc, eps, 1, hb1, b1);

  // ---- fused: x2 -> h2 -> t3 ----
  fused_mid<<<mmBlocks, 256, 0, stream>>>(b1, WH2a, hb2,
                                          bng + HID, bnb + HID, bnm + HID, bnv + HID,
                                          WH1b, b0, N_NODES);
  gather_kernel<<<nodeWaveBlocks, 256, 0, stream>>>(b0, row_ptr, esrc, eps, 2, hb1 + HID, b1);

  // ---- fused tail: x3 -> h3 -> hL -> P1,P2 ----
  fused_tail<<<mmBlocks, 256, 0, stream>>>(b1, WH2b, hb2 + HID,
                                           bng + 2 * HID, bnb + 2 * HID,
                                           bnm + 2 * HID, bnv + 2 * HID,
                                           WTL, lin_b, WTI,
                                           b0, b2, N_NODES);

  pair_mfma<<<pairBlocks, 256, 0, stream>>>(b0, b2, ppi, idx,
                                            int_b1, W2T, int_b2, out);
}